// Round 1
// 2223.963 us; speedup vs baseline: 1.0398x; 1.0398x over previous
//
#include <hip/hip_runtime.h>
#include <math.h>

typedef __bf16 bf16;
typedef __bf16 bf16x8 __attribute__((ext_vector_type(8)));
typedef float f32x4 __attribute__((ext_vector_type(4)));

// Problem dims
#define NQ   32
#define NN_  128
#define TT   352
#define DD   768
#define NH   8
#define HDIM 96
#define LSEQ 512
#define TSPLIT 160          // NQ + NN
#define FFD  3072
#define NLAYER 6
#define NBATCH 16

// ---------------------------------------------------------------------------
// bt-GEMM (bf16 internal): C[M,N] = act(alpha * A[M,K] @ Bt[N,K]^T + bias[N])
// 128x128 tile, BK=32, 256 threads (4 waves, 2x2 of 64x64), mfma 16x16x32.
// m97-style staging: global_load_lds width=16, LDS dest = wave base + lane*16B.
//
// R1 changes:
//  * T2 LDS swizzle: fragment reads As[(row*32+quad*8)] had row stride 64B ->
//    16 lanes of a quad-group hit 2 granule slots = 8-way bank conflict
//    (4.7M SQ_LDS_BANK_CONFLICT/dispatch, MfmaUtil capped ~17%). Swizzle 16B
//    granules S(g) = g ^ ((g>>2)&7). global_load_lds writes linearly, so the
//    WRITE side pre-swizzles the global SOURCE: lane at linear granule G
//    fetches gd = S^-1(G) = G ^ (((G>>2)&7) ^ ((G>>4)&1)); READ side applies
//    S. Bijective within 8-granule (2-row) groups -> coalescing preserved.
//  * T1 chunked XCD swizzle (all grids %8==0): n-blocks sharing an A m-panel
//    land on one XCD's L2 (FF2 re-fetched A ~3x: 156MB vs 55MB ideal).
// ---------------------------------------------------------------------------
template <int ACT>
__global__ __launch_bounds__(256) void gemm_bt(
    const bf16* __restrict__ A, const bf16* __restrict__ Bt,
    bf16* __restrict__ C, const float* __restrict__ bias,
    int K, int lda, int ldb, int ldc, float alpha, int Nstore)
{
    __shared__ __attribute__((aligned(16))) bf16 As[128 * 32];
    __shared__ __attribute__((aligned(16))) bf16 Bs[128 * 32];

    // T1: XCD-aware chunked block swizzle (bijective; guarded by %8)
    const int nwg = gridDim.x * gridDim.y;
    int id = blockIdx.y * gridDim.x + blockIdx.x;
    if ((nwg & 7) == 0) {
        const int chunk = nwg >> 3;
        id = (id & 7) * chunk + (id >> 3);
    }
    const int bx = id % gridDim.x, by = id / gridDim.x;
    const int n0 = bx * 128, m0 = by * 128;

    const int t = threadIdx.x;
    const int w = t >> 6, l = t & 63;
    const int wm = w >> 1, wn = w & 1;
    const int lr = l & 15, quad = l >> 4;

    f32x4 acc[4][4] = {};

    // staging: linear LDS granule G = w*128 + c*64 + l; source granule
    // gd = S^-1(G); row = gd>>2 (4 granules of 8 elems per 32-elem row).
    const int G0 = w * 128 + l;
    const int G1 = G0 + 64;
    const int gd0 = G0 ^ (((G0 >> 2) & 7) ^ ((G0 >> 4) & 1));
    const int gd1 = G1 ^ (((G1 >> 2) & 7) ^ ((G1 >> 4) & 1));
    const int r0 = gd0 >> 2, c0 = (gd0 & 3) * 8;
    const int r1 = gd1 >> 2, c1 = (gd1 & 3) * 8;

    bf16* ldsA0 = &As[w * 1024];
    bf16* ldsA1 = &As[w * 1024 + 512];
    bf16* ldsB0 = &Bs[w * 1024];
    bf16* ldsB1 = &Bs[w * 1024 + 512];
    const bf16* a0 = A  + (size_t)(m0 + r0) * lda + c0;
    const bf16* a1 = A  + (size_t)(m0 + r1) * lda + c1;
    const bf16* b0 = Bt + (size_t)(n0 + r0) * ldb + c0;
    const bf16* b1 = Bt + (size_t)(n0 + r1) * ldb + c1;

    for (int k0 = 0; k0 < K; k0 += 32) {
        __syncthreads();
        __builtin_amdgcn_global_load_lds(
            (const __attribute__((address_space(1))) void*)(a0 + k0),
            (__attribute__((address_space(3))) void*)ldsA0, 16, 0, 0);
        __builtin_amdgcn_global_load_lds(
            (const __attribute__((address_space(1))) void*)(a1 + k0),
            (__attribute__((address_space(3))) void*)ldsA1, 16, 0, 0);
        __builtin_amdgcn_global_load_lds(
            (const __attribute__((address_space(1))) void*)(b0 + k0),
            (__attribute__((address_space(3))) void*)ldsB0, 16, 0, 0);
        __builtin_amdgcn_global_load_lds(
            (const __attribute__((address_space(1))) void*)(b1 + k0),
            (__attribute__((address_space(3))) void*)ldsB1, 16, 0, 0);
        __syncthreads();

        bf16x8 af[4], bf_[4];
#pragma unroll
        for (int i = 0; i < 4; ++i) {
            const int row = wm * 64 + i * 16 + lr;
            const int eo = (row * 32 + quad * 8) ^ ((row & 7) << 3);
            af[i] = *(const bf16x8*)&As[eo];
        }
#pragma unroll
        for (int j = 0; j < 4; ++j) {
            const int row = wn * 64 + j * 16 + lr;
            const int eo = (row * 32 + quad * 8) ^ ((row & 7) << 3);
            bf_[j] = *(const bf16x8*)&Bs[eo];
        }
#pragma unroll
        for (int i = 0; i < 4; ++i)
#pragma unroll
            for (int j = 0; j < 4; ++j)
                acc[i][j] = __builtin_amdgcn_mfma_f32_16x16x32_bf16(af[i], bf_[j], acc[i][j], 0, 0, 0);
    }

#pragma unroll
    for (int i = 0; i < 4; ++i) {
        const int grow = m0 + wm * 64 + i * 16 + quad * 4;
#pragma unroll
        for (int j = 0; j < 4; ++j) {
            const int gcol = n0 + wn * 64 + j * 16 + lr;
            if (gcol >= Nstore) continue;
            float bv = bias ? bias[gcol] : 0.0f;
#pragma unroll
            for (int r = 0; r < 4; ++r) {
                float v = acc[i][j][r] * alpha + bv;
                if (ACT == 1) v = 0.5f * v * (1.0f + erff(v * 0.70710678118654752f));
                C[(size_t)(grow + r) * ldc + gcol] = (bf16)v;
            }
        }
    }
}

// ---------------------------------------------------------------------------
// Flash attention with ITG prefix-LM mask.
// Block = 256 thr (4 waves). Block handles 64 Q-rows of one (b,h).
// Wave w owns Q-rows [w*16, w*16+16). K/V tiles of 64 cols, online softmax.
// Structural tile skip: tile (q0,j0) fully masked iff j0>=TSPLIT && j0>q0+63
// (prefix rows can't see text; causal within text) — skipped tiles contribute
// exp(~-1e9)=0 exactly in fp32, matching the reference's additive -1e9 mask.
// qkv: [B*512][2304] rows b*512+l; Q at h*96, K +768, V +1536.
// ctx: [B*512][768].
// ---------------------------------------------------------------------------
__global__ __launch_bounds__(256) void flash_attn(
    const bf16* __restrict__ qkv, bf16* __restrict__ ctx,
    const int* __restrict__ tatts, const int* __restrict__ gmask)
{
    // pads chosen for conflict-free b128 reads: 104 = 96+8 (stride 208 B),
    // 72 = 64+8 (stride 144 B == 4 banks mod 32 -> 2-way, free).
    __shared__ __attribute__((aligned(16))) bf16 Qs[64 * 104];
    __shared__ __attribute__((aligned(16))) bf16 Ks[64 * 104];
    __shared__ __attribute__((aligned(16))) bf16 Vs[96 * 72];   // V^T tile
    __shared__ __attribute__((aligned(16))) bf16 Ps[64 * 72];
    __shared__ int keep[512];

    const int qt = blockIdx.x;       // 0..7
    const int bh = blockIdx.y;       // 0..127
    const int b = bh >> 3, h = bh & 7;
    const int q0 = qt * 64;
    const int t = threadIdx.x;
    const int w = t >> 6, l = t & 63;
    const int lr = l & 15, quad = l >> 4;
    const float scale = 0.10206207261596577f;  // 1/sqrt(96)

    const bf16* qbase = qkv + (size_t)b * 512 * 2304 + h * 96;
    const bf16* kbase = qbase + 768;
    const bf16* vbase = qbase + 1536;

    // keep vector for this batch
    for (int j = t; j < 512; j += 256)
        keep[j] = (j < NQ) ? 1 : (j < TSPLIT ? gmask[b * NN_ + j - NQ]
                                             : tatts[b * TT + j - TSPLIT]);

    // stage Q tile (64 x 96), rows q0..q0+63
#pragma unroll
    for (int c = 0; c < 3; ++c) {
        const int idx = t * 8 + c * 2048;
        const int r = idx / 96, d = idx % 96;
        *(bf16x8*)&Qs[r * 104 + d] =
            *(const bf16x8*)&qbase[(size_t)(q0 + r) * 2304 + d];
    }
    __syncthreads();

    // this lane's 4 row indices / keeps (rows w*16 + quad*4 + r)
    int ki[4];
    int ig[4];
#pragma unroll
    for (int r = 0; r < 4; ++r) {
        ig[r] = q0 + w * 16 + quad * 4 + r;
        ki[r] = keep[ig[r]];
    }

    float m_run[4] = {-1e30f, -1e30f, -1e30f, -1e30f};
    float l_run[4] = {0.f, 0.f, 0.f, 0.f};
    f32x4 oc[6] = {};

    const int JMAX = (qt < 3) ? 128 : q0;
    for (int j0 = 0; j0 <= JMAX; j0 += 64) {
        __syncthreads();    // prior tile's PV reads of Ks/Vs/Ps complete
        // stage K tile and transposed V tile
#pragma unroll
        for (int c = 0; c < 3; ++c) {
            const int idx = t * 8 + c * 2048;
            const int r = idx / 96, d = idx % 96;
            *(bf16x8*)&Ks[r * 104 + d] =
                *(const bf16x8*)&kbase[(size_t)(j0 + r) * 2304 + d];
            bf16x8 vv = *(const bf16x8*)&vbase[(size_t)(j0 + r) * 2304 + d];
#pragma unroll
            for (int jj = 0; jj < 8; ++jj)
                Vs[(d + jj) * 72 + r] = vv[jj];
        }
        __syncthreads();

        // S tile: this wave's 16 rows x 64 cols
        bf16x8 aq[3];
#pragma unroll
        for (int ds = 0; ds < 3; ++ds)
            aq[ds] = *(const bf16x8*)&Qs[(w * 16 + lr) * 104 + ds * 32 + quad * 8];
        f32x4 sc[4];
#pragma unroll
        for (int cb = 0; cb < 4; ++cb) {
            f32x4 a = {};
#pragma unroll
            for (int ds = 0; ds < 3; ++ds) {
                bf16x8 bk = *(const bf16x8*)&Ks[(cb * 16 + lr) * 104 + ds * 32 + quad * 8];
                a = __builtin_amdgcn_mfma_f32_16x16x32_bf16(aq[ds], bk, a, 0, 0, 0);
            }
            sc[cb] = a;
        }

        // scale + mask bias; tile row max
        float tm[4] = {-1e30f, -1e30f, -1e30f, -1e30f};
#pragma unroll
        for (int cb = 0; cb < 4; ++cb) {
            const int jg = j0 + cb * 16 + lr;
            const int kj = keep[jg];
#pragma unroll
            for (int r = 0; r < 4; ++r) {
                const int i = ig[r];
                bool ok = ki[r] && kj;
                if (i < TSPLIT && jg >= TSPLIT) ok = false;           // prefix !see text
                if (i >= TSPLIT && jg >= TSPLIT && i < jg) ok = false; // causal
                float s = sc[cb][r] * scale + (ok ? 0.f : -1e9f);
                sc[cb][r] = s;
                tm[r] = fmaxf(tm[r], s);
            }
        }
#pragma unroll
        for (int off = 1; off < 16; off <<= 1)
#pragma unroll
            for (int r = 0; r < 4; ++r)
                tm[r] = fmaxf(tm[r], __shfl_xor(tm[r], off));

        // online-softmax update
        float alpha_[4], ts[4] = {0.f, 0.f, 0.f, 0.f};
#pragma unroll
        for (int r = 0; r < 4; ++r) {
            const float mn = fmaxf(m_run[r], tm[r]);
            alpha_[r] = __expf(m_run[r] - mn);
            m_run[r] = mn;
            l_run[r] *= alpha_[r];
        }
#pragma unroll
        for (int db = 0; db < 6; ++db)
#pragma unroll
            for (int r = 0; r < 4; ++r)
                oc[db][r] *= alpha_[r];

        // P = exp(S - m), write to LDS (C-layout -> A-layout roundtrip)
#pragma unroll
        for (int cb = 0; cb < 4; ++cb)
#pragma unroll
            for (int r = 0; r < 4; ++r) {
                const float p = __expf(sc[cb][r] - m_run[r]);
                ts[r] += p;
                Ps[(w * 16 + quad * 4 + r) * 72 + cb * 16 + lr] = (bf16)p;
            }
#pragma unroll
        for (int off = 1; off < 16; off <<= 1)
#pragma unroll
            for (int r = 0; r < 4; ++r)
                ts[r] += __shfl_xor(ts[r], off);
#pragma unroll
        for (int r = 0; r < 4; ++r) l_run[r] += ts[r];

        __syncthreads();    // Ps/Vs visible to all lanes

        // O += P @ V
#pragma unroll
        for (int l0 = 0; l0 < 64; l0 += 32) {
            bf16x8 ap = *(const bf16x8*)&Ps[(w * 16 + lr) * 72 + l0 + quad * 8];
#pragma unroll
            for (int db = 0; db < 6; ++db) {
                bf16x8 bv = *(const bf16x8*)&Vs[(db * 16 + lr) * 72 + l0 + quad * 8];
                oc[db] = __builtin_amdgcn_mfma_f32_16x16x32_bf16(ap, bv, oc[db], 0, 0, 0);
            }
        }
    }

    // epilogue: ctx[b][row][h*96 + d] = O / l
#pragma unroll
    for (int r = 0; r < 4; ++r) {
        const float inv = 1.f / l_run[r];
        bf16* orow = ctx + ((size_t)b * 512 + ig[r]) * 768 + h * 96;
#pragma unroll
        for (int db = 0; db < 6; ++db)
            orow[db * 16 + lr] = (bf16)(oc[db][r] * inv);
    }
}

// ---------------------------------------------------------------------------
// transpose fp32 weight [R][C] -> bf16 [C][R]
// ---------------------------------------------------------------------------
__global__ void transpose_w(const float* __restrict__ in, bf16* __restrict__ out,
                            int R, int C)
{
    __shared__ bf16 tile[32][33];
    const int c0 = blockIdx.x * 32, r0 = blockIdx.y * 32;
    const int tx = threadIdx.x & 31, ty = threadIdx.x >> 5;
    for (int i = ty; i < 32; i += 8)
        tile[i][tx] = (bf16)in[(size_t)(r0 + i) * C + c0 + tx];
    __syncthreads();
    for (int i = ty; i < 32; i += 8)
        out[(size_t)(c0 + i) * R + r0 + tx] = tile[tx][i];
}

// fp32 -> bf16 elementwise
__global__ void cvt_bf16(const float* __restrict__ in, bf16* __restrict__ out, int n)
{
    const int idx = blockIdx.x * 256 + threadIdx.x;
    if (idx < n) out[idx] = (bf16)in[idx];
}

// ---------------------------------------------------------------------------
// reductions / LN
// ---------------------------------------------------------------------------
__device__ __forceinline__ void block_reduce_2(float& a, float& b)
{
#pragma unroll
    for (int off = 32; off; off >>= 1) {
        a += __shfl_xor(a, off);
        b += __shfl_xor(b, off);
    }
    __shared__ float sa[4], sb[4];
    const int w = threadIdx.x >> 6;
    if ((threadIdx.x & 63) == 0) { sa[w] = a; sb[w] = b; }
    __syncthreads();
    a = sa[0] + sa[1] + sa[2] + sa[3];
    b = sb[0] + sb[1] + sb[2] + sb[3];
}

// x[row] = LN(concat_src(row) + pos[l] + tok); fp32 inputs, bf16 out
__global__ void embed_ln(const float* __restrict__ qtok, const bf16* __restrict__ gfeat,
                         const float* __restrict__ text, const float* __restrict__ pos,
                         const float* __restrict__ tok, const float* __restrict__ g,
                         const float* __restrict__ bb, bf16* __restrict__ x)
{
    const int row = blockIdx.x;           // b*512 + l
    const int l = row & 511, b = row >> 9;
    const int t = threadIdx.x;

    float vals[3], s = 0.f, sq = 0.f;
#pragma unroll
    for (int c = 0; c < 3; ++c) {
        const int d = t + c * 256;
        float base;
        if (l < NQ)           base = qtok[(size_t)l * DD + d];
        else if (l < TSPLIT)  base = (float)gfeat[((size_t)b * NN_ + (l - NQ)) * DD + d];
        else                  base = text[((size_t)b * TT + (l - TSPLIT)) * DD + d];
        float v = base + pos[(size_t)l * DD + d] + tok[d];
        vals[c] = v; s += v; sq += v * v;
    }
    block_reduce_2(s, sq);
    const float mean = s * (1.f / 768.f);
    const float var = sq * (1.f / 768.f) - mean * mean;
    const float rs = rsqrtf(var + 1e-12f);
    bf16* o = x + (size_t)row * DD;
#pragma unroll
    for (int c = 0; c < 3; ++c) {
        const int d = t + c * 256;
        o[d] = (bf16)((vals[c] - mean) * rs * g[d] + bb[d]);
    }
}

// out[row] = LN(X[row] + Y[row]); safe for out==X; fp32 gains
__global__ void ln_rows(const bf16* __restrict__ X, const bf16* __restrict__ Y,
                        bf16* __restrict__ Out, const float* __restrict__ g,
                        const float* __restrict__ bb)
{
    const int row = blockIdx.x;
    const int t = threadIdx.x;
    const bf16* xr = X + (size_t)row * DD;
    const bf16* yr = Y + (size_t)row * DD;
    float vals[3], s = 0.f, sq = 0.f;
#pragma unroll
    for (int c = 0; c < 3; ++c) {
        const int d = t + c * 256;
        float v = (float)xr[d] + (float)yr[d];
        vals[c] = v; s += v; sq += v * v;
    }
    block_reduce_2(s, sq);
    const float mean = s * (1.f / 768.f);
    const float var = sq * (1.f / 768.f) - mean * mean;
    const float rs = rsqrtf(var + 1e-12f);
    bf16* o = Out + (size_t)row * DD;
#pragma unroll
    for (int c = 0; c < 3; ++c) {
        const int d = t + c * 256;
        o[d] = (bf16)((vals[c] - mean) * rs * g[d] + bb[d]);
    }
}

// d_out[b][t][d] = x[b][TSPLIT+t][d]  (fp32 out)
__global__ void copy_out(const bf16* __restrict__ x, float* __restrict__ out)
{
    const size_t idx = (size_t)blockIdx.x * 256 + threadIdx.x;   // < 16*352*768
    const int d = idx % DD;
    const size_t row = idx / DD;
    const int t = row % TT;
    const int b = row / TT;
    out[idx] = (float)x[((size_t)b * LSEQ + TSPLIT + t) * DD + d];
}

// ---------------------------------------------------------------------------
// host side
// ---------------------------------------------------------------------------
static void launch_gemm(const bf16* A, const bf16* Bt, bf16* C, const float* bias,
                        int M, int K, int lda, int ldb, int ldc,
                        float alpha, int Nstore, int act, hipStream_t stream)
{
    dim3 grid((Nstore + 127) / 128, M / 128, 1);
    if (act)
        gemm_bt<1><<<grid, 256, 0, stream>>>(A, Bt, C, bias, K, lda, ldb, ldc, alpha, Nstore);
    else
        gemm_bt<0><<<grid, 256, 0, stream>>>(A, Bt, C, bias, K, lda, ldb, ldc, alpha, Nstore);
}

extern "C" void kernel_launch(void* const* d_in, const int* in_sizes, int n_in,
                              void* d_out, int out_size, void* d_ws, size_t ws_size,
                              hipStream_t stream)
{
    // Reference dtypes: all float32 except text_atts / graph_mask (int32).
    const float* gnf     = (const float*)d_in[0];
    const float* text    = (const float*)d_in[1];
    const int*   tatts   = (const int*)d_in[2];
    const int*   gmask   = (const int*)d_in[3];
    const float* qtok    = (const float*)d_in[4];
    const float* gproj_w = (const float*)d_in[5];
    const float* gproj_b = (const float*)d_in[6];
    const float* pos     = (const float*)d_in[7];
    const float* tok     = (const float*)d_in[8];
    const float* eg      = (const float*)d_in[9];
    const float* eb      = (const float*)d_in[10];
    const float* qkv_w   = (const float*)d_in[11];
    const float* qkv_b   = (const float*)d_in[12];
    const float* ao_w    = (const float*)d_in[13];
    const float* ao_b    = (const float*)d_in[14];
    const float* ln1g    = (const float*)d_in[15];
    const float* ln1b    = (const float*)d_in[16];
    const float* ff1_w   = (const float*)d_in[17];
    const float* ff1_b   = (const float*)d_in[18];
    const float* ff2_w   = (const float*)d_in[19];
    const float* ff2_b   = (const float*)d_in[20];
    const float* ln2g    = (const float*)d_in[21];
    const float* ln2b    = (const float*)d_in[22];
    float* out = (float*)d_out;

    // ws layout (bf16 elems), 48,758,784 elems = 97.5 MB (ws >= 169 MB verified
    // in round 4 — big path ran). u-region: qkvb (attn) / hbuf (ffn), disjoint.
    bf16* ws   = (bf16*)d_ws;
    bf16* wt1  = ws;                    // 2,359,296
    bf16* wt2  = wt1 + 2359296;         // 2,359,296
    bf16* x    = wt2 + 2359296;         // 6,291,456
    bf16* ctx  = x   + 6291456;         // 6,291,456
    bf16* t1   = ctx + 6291456;         // 6,291,456
    bf16* u    = t1  + 6291456;         // 25,165,824
    bf16* qkvb = u;                     //   18,874,368 (attn phase)
    bf16* hbuf = u;                     //   25,165,824 (ffn phase)
    bf16* gfeat = t1;                   //    1,572,864 (pre-loop)
    bf16* gnfb  = u;                    //    1,572,864 (pre-loop)

    dim3 blk(256);

    // graph projection: gfeat[2048,768] = bf16(gnf) @ bf16(gproj_w) + b
    cvt_bf16<<<6144, blk, 0, stream>>>(gnf, gnfb, 1572864);
    transpose_w<<<dim3(24, 24), blk, 0, stream>>>(gproj_w, wt1, 768, 768);
    launch_gemm(gnfb, wt1, gfeat, gproj_b, 2048, 768, 768, 768, 768,
                1.f, 768, 0, stream);
    embed_ln<<<8192, blk, 0, stream>>>(qtok, gfeat, text, pos, tok, eg, eb, x);

    for (int i = 0; i < NLAYER; ++i) {
        // qkv = x @ qkv_w[i] + b   [8192, 2304]
        transpose_w<<<dim3(72, 24), blk, 0, stream>>>(
            qkv_w + (size_t)i * 768 * 2304, wt1, 768, 2304);
        launch_gemm(x, wt1, qkvb, qkv_b + i * 2304,
                    8192, 768, 768, 768, 2304, 1.f, 2304, 0, stream);
        // fused attention -> ctx [8192, 768]
        flash_attn<<<dim3(8, 128), blk, 0, stream>>>(qkvb, ctx, tatts, gmask);
        // t1 = ctx @ ao_w[i] + b
        transpose_w<<<dim3(24, 24), blk, 0, stream>>>(
            ao_w + (size_t)i * 589824, wt1, 768, 768);
        launch_gemm(ctx, wt1, t1, ao_b + i * 768,
                    8192, 768, 768, 768, 768, 1.f, 768, 0, stream);
        ln_rows<<<8192, blk, 0, stream>>>(x, t1, x, ln1g + i * 768, ln1b + i * 768);

        // ffn
        transpose_w<<<dim3(96, 24), blk, 0, stream>>>(
            ff1_w + (size_t)i * 2359296, wt1, 768, 3072);
        transpose_w<<<dim3(24, 96), blk, 0, stream>>>(
            ff2_w + (size_t)i * 2359296, wt2, 3072, 768);
        launch_gemm(x, wt1, hbuf, ff1_b + i * 3072,
                    8192, 768, 768, 768, 3072, 1.f, 3072, 1, stream);
        launch_gemm(hbuf, wt2, t1, ff2_b + i * 768,
                    8192, 3072, 3072, 3072, 768, 1.f, 768, 0, stream);
        ln_rows<<<8192, blk, 0, stream>>>(x, t1, x, ln2g + i * 768, ln2b + i * 768);
    }

    copy_out<<<16896, blk, 0, stream>>>(x, out);

    (void)in_sizes; (void)n_in; (void)out_size; (void)ws_size;
}

// Round 2
// 2208.258 us; speedup vs baseline: 1.0472x; 1.0071x over previous
//
#include <hip/hip_runtime.h>
#include <math.h>

typedef __bf16 bf16;
typedef __bf16 bf16x8 __attribute__((ext_vector_type(8)));
typedef float f32x4 __attribute__((ext_vector_type(4)));

// Problem dims
#define NQ   32
#define NN_  128
#define TT   352
#define DD   768
#define NH   8
#define HDIM 96
#define LSEQ 512
#define TSPLIT 160          // NQ + NN
#define FFD  3072
#define NLAYER 6
#define NBATCH 16

// ---------------------------------------------------------------------------
// bt-GEMM (bf16 internal): C[M,N] = act(alpha * A[M,K] @ Bt[N,K]^T + bias[N])
// 128x128 tile, BK=32, 256 threads (4 waves, 2x2 of 64x64), mfma 16x16x32.
//
// R2: 2-phase double-buffered pipeline (T3 minimum recipe).
//  R1 post-mortem: SQ_LDS_BANK_CONFLICT was bit-identical with/without the
//  read swizzle (= 16 wave-writes x 8 wraps per block-kstep exactly) -> the
//  counter is inherent global_load_lds write serialization, reads were never
//  conflicted. Read swizzle reverted (pure VALU cost). Chunked XCD swizzle
//  reverted (FF1 89->118us: it destroyed the natural per-XCD 3-column B
//  working set, FETCH 43MB vs 17MB ideal).
//  R2 theory: ~1700-4900 cyc/kstep vs ~300 cyc of work = exposed global->LDS
//  latency (serial stage -> drain -> compute, 2 barriers/kstep). Fix: stage
//  k-tile t+1 into buf^1 BEFORE computing buf, single __syncthreads per
//  kstep (its implicit vmcnt(0) drain lands after the MFMAs).
// ---------------------------------------------------------------------------
#define GLOAD(srcp, dstp)                                                     \
    __builtin_amdgcn_global_load_lds(                                         \
        (const __attribute__((address_space(1))) void*)(srcp),                \
        (__attribute__((address_space(3))) void*)(dstp), 16, 0, 0)

template <int ACT>
__global__ __launch_bounds__(256) void gemm_bt(
    const bf16* __restrict__ A, const bf16* __restrict__ Bt,
    bf16* __restrict__ C, const float* __restrict__ bias,
    int K, int lda, int ldb, int ldc, float alpha, int Nstore)
{
    __shared__ __attribute__((aligned(16))) bf16 As[2 * 128 * 32];
    __shared__ __attribute__((aligned(16))) bf16 Bs[2 * 128 * 32];

    const int n0 = blockIdx.x * 128, m0 = blockIdx.y * 128;
    const int t = threadIdx.x;
    const int w = t >> 6, l = t & 63;
    const int wm = w >> 1, wn = w & 1;
    const int lr = l & 15, quad = l >> 4;

    f32x4 acc[4][4] = {};

    // staging geometry: wave w fills elements [w*1024, (w+1)*1024) of each
    // 128x32 buffer with two 1KB wave-writes; lane l supplies row/col below.
    const int f0 = w * 1024 + l * 8;
    const int ra0 = f0 >> 5, ca0 = f0 & 31;
    const int ra1 = (f0 + 512) >> 5, ca1 = (f0 + 512) & 31;
    const bf16* a0 = A  + (size_t)(m0 + ra0) * lda + ca0;
    const bf16* a1 = A  + (size_t)(m0 + ra1) * lda + ca1;
    const bf16* b0 = Bt + (size_t)(n0 + ra0) * ldb + ca0;
    const bf16* b1 = Bt + (size_t)(n0 + ra1) * ldb + ca1;

    const int nt = K >> 5;

    // prologue: stage k-tile 0 into buffer 0
    {
        bf16* pA = &As[w * 1024];
        bf16* pB = &Bs[w * 1024];
        GLOAD(a0, pA);
        GLOAD(a1, pA + 512);
        GLOAD(b0, pB);
        GLOAD(b1, pB + 512);
    }

    for (int tt = 0; tt < nt; ++tt) {
        __syncthreads();   // drains stage of buf[tt&1]; fences reads of buf[~]
        const int cur = (tt & 1) << 12;        // 0 or 4096 elements
        const int nxt = 4096 - cur;
        if (tt + 1 < nt) {
            const int k0 = (tt + 1) << 5;
            bf16* pA = &As[nxt + w * 1024];
            bf16* pB = &Bs[nxt + w * 1024];
            GLOAD(a0 + k0, pA);
            GLOAD(a1 + k0, pA + 512);
            GLOAD(b0 + k0, pB);
            GLOAD(b1 + k0, pB + 512);
        }

        bf16x8 af[4], bf_[4];
#pragma unroll
        for (int i = 0; i < 4; ++i)
            af[i] = *(const bf16x8*)&As[cur + (wm * 64 + i * 16 + lr) * 32 + quad * 8];
#pragma unroll
        for (int j = 0; j < 4; ++j)
            bf_[j] = *(const bf16x8*)&Bs[cur + (wn * 64 + j * 16 + lr) * 32 + quad * 8];
#pragma unroll
        for (int i = 0; i < 4; ++i)
#pragma unroll
            for (int j = 0; j < 4; ++j)
                acc[i][j] = __builtin_amdgcn_mfma_f32_16x16x32_bf16(af[i], bf_[j], acc[i][j], 0, 0, 0);
    }

#pragma unroll
    for (int i = 0; i < 4; ++i) {
        const int grow = m0 + wm * 64 + i * 16 + quad * 4;
#pragma unroll
        for (int j = 0; j < 4; ++j) {
            const int gcol = n0 + wn * 64 + j * 16 + lr;
            if (gcol >= Nstore) continue;
            float bv = bias ? bias[gcol] : 0.0f;
#pragma unroll
            for (int r = 0; r < 4; ++r) {
                float v = acc[i][j][r] * alpha + bv;
                if (ACT == 1) v = 0.5f * v * (1.0f + erff(v * 0.70710678118654752f));
                C[(size_t)(grow + r) * ldc + gcol] = (bf16)v;
            }
        }
    }
}

// ---------------------------------------------------------------------------
// Flash attention with ITG prefix-LM mask.
// Block = 256 thr (4 waves). Block handles 64 Q-rows of one (b,h).
// Wave w owns Q-rows [w*16, w*16+16). K/V tiles of 64 cols, online softmax.
// Structural tile skip: tile (q0,j0) fully masked iff j0>=TSPLIT && j0>q0+63
// (prefix rows can't see text; causal within text) — skipped tiles contribute
// exp(~-1e9)=0 exactly in fp32, matching the reference's additive -1e9 mask.
// qkv: [B*512][2304] rows b*512+l; Q at h*96, K +768, V +1536.
// ctx: [B*512][768].
// ---------------------------------------------------------------------------
__global__ __launch_bounds__(256) void flash_attn(
    const bf16* __restrict__ qkv, bf16* __restrict__ ctx,
    const int* __restrict__ tatts, const int* __restrict__ gmask)
{
    // pads chosen for conflict-free b128 reads: 104 = 96+8 (stride 208 B),
    // 72 = 64+8 (stride 144 B == 4 banks mod 32 -> 2-way, free).
    __shared__ __attribute__((aligned(16))) bf16 Qs[64 * 104];
    __shared__ __attribute__((aligned(16))) bf16 Ks[64 * 104];
    __shared__ __attribute__((aligned(16))) bf16 Vs[96 * 72];   // V^T tile
    __shared__ __attribute__((aligned(16))) bf16 Ps[64 * 72];
    __shared__ int keep[512];

    const int qt = blockIdx.x;       // 0..7
    const int bh = blockIdx.y;       // 0..127
    const int b = bh >> 3, h = bh & 7;
    const int q0 = qt * 64;
    const int t = threadIdx.x;
    const int w = t >> 6, l = t & 63;
    const int lr = l & 15, quad = l >> 4;
    const float scale = 0.10206207261596577f;  // 1/sqrt(96)

    const bf16* qbase = qkv + (size_t)b * 512 * 2304 + h * 96;
    const bf16* kbase = qbase + 768;
    const bf16* vbase = qbase + 1536;

    // keep vector for this batch
    for (int j = t; j < 512; j += 256)
        keep[j] = (j < NQ) ? 1 : (j < TSPLIT ? gmask[b * NN_ + j - NQ]
                                             : tatts[b * TT + j - TSPLIT]);

    // stage Q tile (64 x 96), rows q0..q0+63
#pragma unroll
    for (int c = 0; c < 3; ++c) {
        const int idx = t * 8 + c * 2048;
        const int r = idx / 96, d = idx % 96;
        *(bf16x8*)&Qs[r * 104 + d] =
            *(const bf16x8*)&qbase[(size_t)(q0 + r) * 2304 + d];
    }
    __syncthreads();

    // this lane's 4 row indices / keeps (rows w*16 + quad*4 + r)
    int ki[4];
    int ig[4];
#pragma unroll
    for (int r = 0; r < 4; ++r) {
        ig[r] = q0 + w * 16 + quad * 4 + r;
        ki[r] = keep[ig[r]];
    }

    float m_run[4] = {-1e30f, -1e30f, -1e30f, -1e30f};
    float l_run[4] = {0.f, 0.f, 0.f, 0.f};
    f32x4 oc[6] = {};

    const int JMAX = (qt < 3) ? 128 : q0;
    for (int j0 = 0; j0 <= JMAX; j0 += 64) {
        __syncthreads();    // prior tile's PV reads of Ks/Vs/Ps complete
        // stage K tile and transposed V tile
#pragma unroll
        for (int c = 0; c < 3; ++c) {
            const int idx = t * 8 + c * 2048;
            const int r = idx / 96, d = idx % 96;
            *(bf16x8*)&Ks[r * 104 + d] =
                *(const bf16x8*)&kbase[(size_t)(j0 + r) * 2304 + d];
            bf16x8 vv = *(const bf16x8*)&vbase[(size_t)(j0 + r) * 2304 + d];
#pragma unroll
            for (int jj = 0; jj < 8; ++jj)
                Vs[(d + jj) * 72 + r] = vv[jj];
        }
        __syncthreads();

        // S tile: this wave's 16 rows x 64 cols
        bf16x8 aq[3];
#pragma unroll
        for (int ds = 0; ds < 3; ++ds)
            aq[ds] = *(const bf16x8*)&Qs[(w * 16 + lr) * 104 + ds * 32 + quad * 8];
        f32x4 sc[4];
#pragma unroll
        for (int cb = 0; cb < 4; ++cb) {
            f32x4 a = {};
#pragma unroll
            for (int ds = 0; ds < 3; ++ds) {
                bf16x8 bk = *(const bf16x8*)&Ks[(cb * 16 + lr) * 104 + ds * 32 + quad * 8];
                a = __builtin_amdgcn_mfma_f32_16x16x32_bf16(aq[ds], bk, a, 0, 0, 0);
            }
            sc[cb] = a;
        }

        // scale + mask bias; tile row max
        float tm[4] = {-1e30f, -1e30f, -1e30f, -1e30f};
#pragma unroll
        for (int cb = 0; cb < 4; ++cb) {
            const int jg = j0 + cb * 16 + lr;
            const int kj = keep[jg];
#pragma unroll
            for (int r = 0; r < 4; ++r) {
                const int i = ig[r];
                bool ok = ki[r] && kj;
                if (i < TSPLIT && jg >= TSPLIT) ok = false;           // prefix !see text
                if (i >= TSPLIT && jg >= TSPLIT && i < jg) ok = false; // causal
                float s = sc[cb][r] * scale + (ok ? 0.f : -1e9f);
                sc[cb][r] = s;
                tm[r] = fmaxf(tm[r], s);
            }
        }
#pragma unroll
        for (int off = 1; off < 16; off <<= 1)
#pragma unroll
            for (int r = 0; r < 4; ++r)
                tm[r] = fmaxf(tm[r], __shfl_xor(tm[r], off));

        // online-softmax update
        float alpha_[4], ts[4] = {0.f, 0.f, 0.f, 0.f};
#pragma unroll
        for (int r = 0; r < 4; ++r) {
            const float mn = fmaxf(m_run[r], tm[r]);
            alpha_[r] = __expf(m_run[r] - mn);
            m_run[r] = mn;
            l_run[r] *= alpha_[r];
        }
#pragma unroll
        for (int db = 0; db < 6; ++db)
#pragma unroll
            for (int r = 0; r < 4; ++r)
                oc[db][r] *= alpha_[r];

        // P = exp(S - m), write to LDS (C-layout -> A-layout roundtrip)
#pragma unroll
        for (int cb = 0; cb < 4; ++cb)
#pragma unroll
            for (int r = 0; r < 4; ++r) {
                const float p = __expf(sc[cb][r] - m_run[r]);
                ts[r] += p;
                Ps[(w * 16 + quad * 4 + r) * 72 + cb * 16 + lr] = (bf16)p;
            }
#pragma unroll
        for (int off = 1; off < 16; off <<= 1)
#pragma unroll
            for (int r = 0; r < 4; ++r)
                ts[r] += __shfl_xor(ts[r], off);
#pragma unroll
        for (int r = 0; r < 4; ++r) l_run[r] += ts[r];

        __syncthreads();    // Ps/Vs visible to all lanes

        // O += P @ V
#pragma unroll
        for (int l0 = 0; l0 < 64; l0 += 32) {
            bf16x8 ap = *(const bf16x8*)&Ps[(w * 16 + lr) * 72 + l0 + quad * 8];
#pragma unroll
            for (int db = 0; db < 6; ++db) {
                bf16x8 bv = *(const bf16x8*)&Vs[(db * 16 + lr) * 72 + l0 + quad * 8];
                oc[db] = __builtin_amdgcn_mfma_f32_16x16x32_bf16(ap, bv, oc[db], 0, 0, 0);
            }
        }
    }

    // epilogue: ctx[b][row][h*96 + d] = O / l
#pragma unroll
    for (int r = 0; r < 4; ++r) {
        const float inv = 1.f / l_run[r];
        bf16* orow = ctx + ((size_t)b * 512 + ig[r]) * 768 + h * 96;
#pragma unroll
        for (int db = 0; db < 6; ++db)
            orow[db * 16 + lr] = (bf16)(oc[db][r] * inv);
    }
}

// ---------------------------------------------------------------------------
// transpose fp32 weight [R][C] -> bf16 [C][R]
// ---------------------------------------------------------------------------
__global__ void transpose_w(const float* __restrict__ in, bf16* __restrict__ out,
                            int R, int C)
{
    __shared__ bf16 tile[32][33];
    const int c0 = blockIdx.x * 32, r0 = blockIdx.y * 32;
    const int tx = threadIdx.x & 31, ty = threadIdx.x >> 5;
    for (int i = ty; i < 32; i += 8)
        tile[i][tx] = (bf16)in[(size_t)(r0 + i) * C + c0 + tx];
    __syncthreads();
    for (int i = ty; i < 32; i += 8)
        out[(size_t)(c0 + i) * R + r0 + tx] = tile[tx][i];
}

// fp32 -> bf16 elementwise
__global__ void cvt_bf16(const float* __restrict__ in, bf16* __restrict__ out, int n)
{
    const int idx = blockIdx.x * 256 + threadIdx.x;
    if (idx < n) out[idx] = (bf16)in[idx];
}

// ---------------------------------------------------------------------------
// reductions / LN
// ---------------------------------------------------------------------------
__device__ __forceinline__ void block_reduce_2(float& a, float& b)
{
#pragma unroll
    for (int off = 32; off; off >>= 1) {
        a += __shfl_xor(a, off);
        b += __shfl_xor(b, off);
    }
    __shared__ float sa[4], sb[4];
    const int w = threadIdx.x >> 6;
    if ((threadIdx.x & 63) == 0) { sa[w] = a; sb[w] = b; }
    __syncthreads();
    a = sa[0] + sa[1] + sa[2] + sa[3];
    b = sb[0] + sb[1] + sb[2] + sb[3];
}

// x[row] = LN(concat_src(row) + pos[l] + tok); fp32 inputs, bf16 out
__global__ void embed_ln(const float* __restrict__ qtok, const bf16* __restrict__ gfeat,
                         const float* __restrict__ text, const float* __restrict__ pos,
                         const float* __restrict__ tok, const float* __restrict__ g,
                         const float* __restrict__ bb, bf16* __restrict__ x)
{
    const int row = blockIdx.x;           // b*512 + l
    const int l = row & 511, b = row >> 9;
    const int t = threadIdx.x;

    float vals[3], s = 0.f, sq = 0.f;
#pragma unroll
    for (int c = 0; c < 3; ++c) {
        const int d = t + c * 256;
        float base;
        if (l < NQ)           base = qtok[(size_t)l * DD + d];
        else if (l < TSPLIT)  base = (float)gfeat[((size_t)b * NN_ + (l - NQ)) * DD + d];
        else                  base = text[((size_t)b * TT + (l - TSPLIT)) * DD + d];
        float v = base + pos[(size_t)l * DD + d] + tok[d];
        vals[c] = v; s += v; sq += v * v;
    }
    block_reduce_2(s, sq);
    const float mean = s * (1.f / 768.f);
    const float var = sq * (1.f / 768.f) - mean * mean;
    const float rs = rsqrtf(var + 1e-12f);
    bf16* o = x + (size_t)row * DD;
#pragma unroll
    for (int c = 0; c < 3; ++c) {
        const int d = t + c * 256;
        o[d] = (bf16)((vals[c] - mean) * rs * g[d] + bb[d]);
    }
}

// out[row] = LN(X[row] + Y[row]); safe for out==X; fp32 gains
__global__ void ln_rows(const bf16* __restrict__ X, const bf16* __restrict__ Y,
                        bf16* __restrict__ Out, const float* __restrict__ g,
                        const float* __restrict__ bb)
{
    const int row = blockIdx.x;
    const int t = threadIdx.x;
    const bf16* xr = X + (size_t)row * DD;
    const bf16* yr = Y + (size_t)row * DD;
    float vals[3], s = 0.f, sq = 0.f;
#pragma unroll
    for (int c = 0; c < 3; ++c) {
        const int d = t + c * 256;
        float v = (float)xr[d] + (float)yr[d];
        vals[c] = v; s += v; sq += v * v;
    }
    block_reduce_2(s, sq);
    const float mean = s * (1.f / 768.f);
    const float var = sq * (1.f / 768.f) - mean * mean;
    const float rs = rsqrtf(var + 1e-12f);
    bf16* o = Out + (size_t)row * DD;
#pragma unroll
    for (int c = 0; c < 3; ++c) {
        const int d = t + c * 256;
        o[d] = (bf16)((vals[c] - mean) * rs * g[d] + bb[d]);
    }
}

// d_out[b][t][d] = x[b][TSPLIT+t][d]  (fp32 out)
__global__ void copy_out(const bf16* __restrict__ x, float* __restrict__ out)
{
    const size_t idx = (size_t)blockIdx.x * 256 + threadIdx.x;   // < 16*352*768
    const int d = idx % DD;
    const size_t row = idx / DD;
    const int t = row % TT;
    const int b = row / TT;
    out[idx] = (float)x[((size_t)b * LSEQ + TSPLIT + t) * DD + d];
}

// ---------------------------------------------------------------------------
// host side
// ---------------------------------------------------------------------------
static void launch_gemm(const bf16* A, const bf16* Bt, bf16* C, const float* bias,
                        int M, int K, int lda, int ldb, int ldc,
                        float alpha, int Nstore, int act, hipStream_t stream)
{
    dim3 grid((Nstore + 127) / 128, M / 128, 1);
    if (act)
        gemm_bt<1><<<grid, 256, 0, stream>>>(A, Bt, C, bias, K, lda, ldb, ldc, alpha, Nstore);
    else
        gemm_bt<0><<<grid, 256, 0, stream>>>(A, Bt, C, bias, K, lda, ldb, ldc, alpha, Nstore);
}

extern "C" void kernel_launch(void* const* d_in, const int* in_sizes, int n_in,
                              void* d_out, int out_size, void* d_ws, size_t ws_size,
                              hipStream_t stream)
{
    // Reference dtypes: all float32 except text_atts / graph_mask (int32).
    const float* gnf     = (const float*)d_in[0];
    const float* text    = (const float*)d_in[1];
    const int*   tatts   = (const int*)d_in[2];
    const int*   gmask   = (const int*)d_in[3];
    const float* qtok    = (const float*)d_in[4];
    const float* gproj_w = (const float*)d_in[5];
    const float* gproj_b = (const float*)d_in[6];
    const float* pos     = (const float*)d_in[7];
    const float* tok     = (const float*)d_in[8];
    const float* eg      = (const float*)d_in[9];
    const float* eb      = (const float*)d_in[10];
    const float* qkv_w   = (const float*)d_in[11];
    const float* qkv_b   = (const float*)d_in[12];
    const float* ao_w    = (const float*)d_in[13];
    const float* ao_b    = (const float*)d_in[14];
    const float* ln1g    = (const float*)d_in[15];
    const float* ln1b    = (const float*)d_in[16];
    const float* ff1_w   = (const float*)d_in[17];
    const float* ff1_b   = (const float*)d_in[18];
    const float* ff2_w   = (const float*)d_in[19];
    const float* ff2_b   = (const float*)d_in[20];
    const float* ln2g    = (const float*)d_in[21];
    const float* ln2b    = (const float*)d_in[22];
    float* out = (float*)d_out;

    // ws layout (bf16 elems), 48,758,784 elems = 97.5 MB (ws >= 169 MB verified
    // in round 4 — big path ran). u-region: qkvb (attn) / hbuf (ffn), disjoint.
    bf16* ws   = (bf16*)d_ws;
    bf16* wt1  = ws;                    // 2,359,296
    bf16* wt2  = wt1 + 2359296;         // 2,359,296
    bf16* x    = wt2 + 2359296;         // 6,291,456
    bf16* ctx  = x   + 6291456;         // 6,291,456
    bf16* t1   = ctx + 6291456;         // 6,291,456
    bf16* u    = t1  + 6291456;         // 25,165,824
    bf16* qkvb = u;                     //   18,874,368 (attn phase)
    bf16* hbuf = u;                     //   25,165,824 (ffn phase)
    bf16* gfeat = t1;                   //    1,572,864 (pre-loop)
    bf16* gnfb  = u;                    //    1,572,864 (pre-loop)

    dim3 blk(256);

    // graph projection: gfeat[2048,768] = bf16(gnf) @ bf16(gproj_w) + b
    cvt_bf16<<<6144, blk, 0, stream>>>(gnf, gnfb, 1572864);
    transpose_w<<<dim3(24, 24), blk, 0, stream>>>(gproj_w, wt1, 768, 768);
    launch_gemm(gnfb, wt1, gfeat, gproj_b, 2048, 768, 768, 768, 768,
                1.f, 768, 0, stream);
    embed_ln<<<8192, blk, 0, stream>>>(qtok, gfeat, text, pos, tok, eg, eb, x);

    for (int i = 0; i < NLAYER; ++i) {
        // qkv = x @ qkv_w[i] + b   [8192, 2304]
        transpose_w<<<dim3(72, 24), blk, 0, stream>>>(
            qkv_w + (size_t)i * 768 * 2304, wt1, 768, 2304);
        launch_gemm(x, wt1, qkvb, qkv_b + i * 2304,
                    8192, 768, 768, 768, 2304, 1.f, 2304, 0, stream);
        // fused attention -> ctx [8192, 768]
        flash_attn<<<dim3(8, 128), blk, 0, stream>>>(qkvb, ctx, tatts, gmask);
        // t1 = ctx @ ao_w[i] + b
        transpose_w<<<dim3(24, 24), blk, 0, stream>>>(
            ao_w + (size_t)i * 589824, wt1, 768, 768);
        launch_gemm(ctx, wt1, t1, ao_b + i * 768,
                    8192, 768, 768, 768, 768, 1.f, 768, 0, stream);
        ln_rows<<<8192, blk, 0, stream>>>(x, t1, x, ln1g + i * 768, ln1b + i * 768);

        // ffn
        transpose_w<<<dim3(96, 24), blk, 0, stream>>>(
            ff1_w + (size_t)i * 2359296, wt1, 768, 3072);
        transpose_w<<<dim3(24, 96), blk, 0, stream>>>(
            ff2_w + (size_t)i * 2359296, wt2, 3072, 768);
        launch_gemm(x, wt1, hbuf, ff1_b + i * 3072,
                    8192, 768, 768, 768, 3072, 1.f, 3072, 1, stream);
        launch_gemm(hbuf, wt2, t1, ff2_b + i * 768,
                    8192, 3072, 3072, 3072, 768, 1.f, 768, 0, stream);
        ln_rows<<<8192, blk, 0, stream>>>(x, t1, x, ln2g + i * 768, ln2b + i * 768);
    }

    copy_out<<<16896, blk, 0, stream>>>(x, out);

    (void)in_sizes; (void)n_in; (void)out_size; (void)ws_size;
}

// Round 3
// 2180.167 us; speedup vs baseline: 1.0607x; 1.0129x over previous
//
#include <hip/hip_runtime.h>
#include <math.h>

typedef __bf16 bf16;
typedef __bf16 bf16x8 __attribute__((ext_vector_type(8)));
typedef float f32x4 __attribute__((ext_vector_type(4)));

// Problem dims
#define NQ   32
#define NN_  128
#define TT   352
#define DD   768
#define NH   8
#define HDIM 96
#define LSEQ 512
#define TSPLIT 160          // NQ + NN
#define FFD  3072
#define NLAYER 6
#define NBATCH 16

// ---------------------------------------------------------------------------
// bt-GEMM (bf16 internal): C[M,N] = act(alpha * A[M,K] @ Bt[N,K]^T + bias[N])
// 128x128 tile, BK=32, 256 threads (4 waves, 2x2 of 64x64), mfma 16x16x32.
//
// R3: depth-2 counted-vmcnt pipeline (T4), 3 LDS buffers (48 KB, 3 blk/CU).
//  R2 post-mortem: 2-buffer 2-phase helped (FF1 118->81) but __syncthreads'
//  implicit vmcnt(0) drains the prefetch issued in the SAME iteration ->
//  hiding window = 1 compute phase (~500 cyc) vs ~900 cyc load latency;
//  ~60% of per-kstep time still exposed (MfmaUtil 19%, nothing saturated).
//  R3 structure per K-step (tile T):
//    s_waitcnt vmcnt(4)   — own tile-T loads done (issued 2 phases ago);
//                           tile-T+1's 4 loads stay in flight across barrier
//    s_barrier            — cross-wave: ALL waves' tile-T loads landed
//    sched_barrier(0)     — pin ds_reads below the barrier (rule #18)
//    stage tile T+2 -> buf[(T+2)%3]   (WAR-safe: last read in iter T-1,
//                           consumed by MFMAs issued before this barrier)
//    ds_read buf[T%3] + 16 MFMA
//  Last iter waits vmcnt(0). SQ_LDS_BANK_CONFLICT = 4,718,592 is inherent
//  global_load_lds write serialization (16 wave-writes x 8 wraps / kstep),
//  not a read conflict — do not chase it.
// ---------------------------------------------------------------------------
#define GLOAD(srcp, dstp)                                                     \
    __builtin_amdgcn_global_load_lds(                                         \
        (const __attribute__((address_space(1))) void*)(srcp),                \
        (__attribute__((address_space(3))) void*)(dstp), 16, 0, 0)

template <int ACT>
__global__ __launch_bounds__(256) void gemm_bt(
    const bf16* __restrict__ A, const bf16* __restrict__ Bt,
    bf16* __restrict__ C, const float* __restrict__ bias,
    int K, int lda, int ldb, int ldc, float alpha, int Nstore)
{
    __shared__ __attribute__((aligned(16))) bf16 As[3 * 4096];
    __shared__ __attribute__((aligned(16))) bf16 Bs[3 * 4096];

    const int n0 = blockIdx.x * 128, m0 = blockIdx.y * 128;
    const int t = threadIdx.x;
    const int w = t >> 6, l = t & 63;
    const int wm = w >> 1, wn = w & 1;
    const int lr = l & 15, quad = l >> 4;

    f32x4 acc[4][4] = {};

    // staging geometry: wave w fills elements [w*1024, (w+1)*1024) of each
    // 128x32 buffer with two 1KB wave-writes; lane l supplies row/col below.
    const int f0 = w * 1024 + l * 8;
    const int ra0 = f0 >> 5, ca0 = f0 & 31;
    const int ra1 = (f0 + 512) >> 5, ca1 = (f0 + 512) & 31;
    const bf16* a0 = A  + (size_t)(m0 + ra0) * lda + ca0;
    const bf16* a1 = A  + (size_t)(m0 + ra1) * lda + ca1;
    const bf16* b0 = Bt + (size_t)(n0 + ra0) * ldb + ca0;
    const bf16* b1 = Bt + (size_t)(n0 + ra1) * ldb + ca1;

    const int nt = K >> 5;              // >= 3 and divisible by 3 for all calls

    // prologue: stage tiles 0,1 into buffers 0,1
    {
        bf16* pA = &As[w * 1024];
        bf16* pB = &Bs[w * 1024];
        GLOAD(a0, pA);        GLOAD(a1, pA + 512);
        GLOAD(b0, pB);        GLOAD(b1, pB + 512);
        pA += 4096;  pB += 4096;
        GLOAD(a0 + 32, pA);   GLOAD(a1 + 32, pA + 512);
        GLOAD(b0 + 32, pB);   GLOAD(b1 + 32, pB + 512);
    }

    int cb = 0;                 // buffer holding tile T
    int wb = 2;                 // buffer for tile T+2
    for (int T = 0; T < nt; ++T) {
        if (T == nt - 1) {
            asm volatile("s_waitcnt vmcnt(0)" ::: "memory");
        } else {
            asm volatile("s_waitcnt vmcnt(4)" ::: "memory");
        }
        __builtin_amdgcn_s_barrier();
        __builtin_amdgcn_sched_barrier(0);

        if (T + 2 < nt) {
            const int k0 = (T + 2) << 5;
            bf16* pA = &As[wb * 4096 + w * 1024];
            bf16* pB = &Bs[wb * 4096 + w * 1024];
            GLOAD(a0 + k0, pA);   GLOAD(a1 + k0, pA + 512);
            GLOAD(b0 + k0, pB);   GLOAD(b1 + k0, pB + 512);
        }

        const int cur = cb << 12;
        bf16x8 af[4], bf_[4];
#pragma unroll
        for (int i = 0; i < 4; ++i)
            af[i] = *(const bf16x8*)&As[cur + (wm * 64 + i * 16 + lr) * 32 + quad * 8];
#pragma unroll
        for (int j = 0; j < 4; ++j)
            bf_[j] = *(const bf16x8*)&Bs[cur + (wn * 64 + j * 16 + lr) * 32 + quad * 8];
#pragma unroll
        for (int i = 0; i < 4; ++i)
#pragma unroll
            for (int j = 0; j < 4; ++j)
                acc[i][j] = __builtin_amdgcn_mfma_f32_16x16x32_bf16(af[i], bf_[j], acc[i][j], 0, 0, 0);

        cb = (cb == 2) ? 0 : cb + 1;
        wb = (wb == 2) ? 0 : wb + 1;
    }

#pragma unroll
    for (int i = 0; i < 4; ++i) {
        const int grow = m0 + wm * 64 + i * 16 + quad * 4;
#pragma unroll
        for (int j = 0; j < 4; ++j) {
            const int gcol = n0 + wn * 64 + j * 16 + lr;
            if (gcol >= Nstore) continue;
            float bv = bias ? bias[gcol] : 0.0f;
#pragma unroll
            for (int r = 0; r < 4; ++r) {
                float v = acc[i][j][r] * alpha + bv;
                if (ACT == 1) v = 0.5f * v * (1.0f + erff(v * 0.70710678118654752f));
                C[(size_t)(grow + r) * ldc + gcol] = (bf16)v;
            }
        }
    }
}

// ---------------------------------------------------------------------------
// Flash attention with ITG prefix-LM mask.
// Block = 256 thr (4 waves). Block handles 64 Q-rows of one (b,h).
// Wave w owns Q-rows [w*16, w*16+16). K/V tiles of 64 cols, online softmax.
// Structural tile skip: tile (q0,j0) fully masked iff j0>=TSPLIT && j0>q0+63
// (prefix rows can't see text; causal within text) — skipped tiles contribute
// exp(~-1e9)=0 exactly in fp32, matching the reference's additive -1e9 mask.
// qkv: [B*512][2304] rows b*512+l; Q at h*96, K +768, V +1536.
// ctx: [B*512][768].
// ---------------------------------------------------------------------------
__global__ __launch_bounds__(256) void flash_attn(
    const bf16* __restrict__ qkv, bf16* __restrict__ ctx,
    const int* __restrict__ tatts, const int* __restrict__ gmask)
{
    // pads chosen for conflict-free b128 reads: 104 = 96+8 (stride 208 B),
    // 72 = 64+8 (stride 144 B == 4 banks mod 32 -> 2-way, free).
    __shared__ __attribute__((aligned(16))) bf16 Qs[64 * 104];
    __shared__ __attribute__((aligned(16))) bf16 Ks[64 * 104];
    __shared__ __attribute__((aligned(16))) bf16 Vs[96 * 72];   // V^T tile
    __shared__ __attribute__((aligned(16))) bf16 Ps[64 * 72];
    __shared__ int keep[512];

    const int qt = blockIdx.x;       // 0..7
    const int bh = blockIdx.y;       // 0..127
    const int b = bh >> 3, h = bh & 7;
    const int q0 = qt * 64;
    const int t = threadIdx.x;
    const int w = t >> 6, l = t & 63;
    const int lr = l & 15, quad = l >> 4;
    const float scale = 0.10206207261596577f;  // 1/sqrt(96)

    const bf16* qbase = qkv + (size_t)b * 512 * 2304 + h * 96;
    const bf16* kbase = qbase + 768;
    const bf16* vbase = qbase + 1536;

    // keep vector for this batch
    for (int j = t; j < 512; j += 256)
        keep[j] = (j < NQ) ? 1 : (j < TSPLIT ? gmask[b * NN_ + j - NQ]
                                             : tatts[b * TT + j - TSPLIT]);

    // stage Q tile (64 x 96), rows q0..q0+63
#pragma unroll
    for (int c = 0; c < 3; ++c) {
        const int idx = t * 8 + c * 2048;
        const int r = idx / 96, d = idx % 96;
        *(bf16x8*)&Qs[r * 104 + d] =
            *(const bf16x8*)&qbase[(size_t)(q0 + r) * 2304 + d];
    }
    __syncthreads();

    // this lane's 4 row indices / keeps (rows w*16 + quad*4 + r)
    int ki[4];
    int ig[4];
#pragma unroll
    for (int r = 0; r < 4; ++r) {
        ig[r] = q0 + w * 16 + quad * 4 + r;
        ki[r] = keep[ig[r]];
    }

    float m_run[4] = {-1e30f, -1e30f, -1e30f, -1e30f};
    float l_run[4] = {0.f, 0.f, 0.f, 0.f};
    f32x4 oc[6] = {};

    const int JMAX = (qt < 3) ? 128 : q0;
    for (int j0 = 0; j0 <= JMAX; j0 += 64) {
        __syncthreads();    // prior tile's PV reads of Ks/Vs/Ps complete
        // stage K tile and transposed V tile
#pragma unroll
        for (int c = 0; c < 3; ++c) {
            const int idx = t * 8 + c * 2048;
            const int r = idx / 96, d = idx % 96;
            *(bf16x8*)&Ks[r * 104 + d] =
                *(const bf16x8*)&kbase[(size_t)(j0 + r) * 2304 + d];
            bf16x8 vv = *(const bf16x8*)&vbase[(size_t)(j0 + r) * 2304 + d];
#pragma unroll
            for (int jj = 0; jj < 8; ++jj)
                Vs[(d + jj) * 72 + r] = vv[jj];
        }
        __syncthreads();

        // S tile: this wave's 16 rows x 64 cols
        bf16x8 aq[3];
#pragma unroll
        for (int ds = 0; ds < 3; ++ds)
            aq[ds] = *(const bf16x8*)&Qs[(w * 16 + lr) * 104 + ds * 32 + quad * 8];
        f32x4 sc[4];
#pragma unroll
        for (int cb = 0; cb < 4; ++cb) {
            f32x4 a = {};
#pragma unroll
            for (int ds = 0; ds < 3; ++ds) {
                bf16x8 bk = *(const bf16x8*)&Ks[(cb * 16 + lr) * 104 + ds * 32 + quad * 8];
                a = __builtin_amdgcn_mfma_f32_16x16x32_bf16(aq[ds], bk, a, 0, 0, 0);
            }
            sc[cb] = a;
        }

        // scale + mask bias; tile row max
        float tm[4] = {-1e30f, -1e30f, -1e30f, -1e30f};
#pragma unroll
        for (int cb = 0; cb < 4; ++cb) {
            const int jg = j0 + cb * 16 + lr;
            const int kj = keep[jg];
#pragma unroll
            for (int r = 0; r < 4; ++r) {
                const int i = ig[r];
                bool ok = ki[r] && kj;
                if (i < TSPLIT && jg >= TSPLIT) ok = false;           // prefix !see text
                if (i >= TSPLIT && jg >= TSPLIT && i < jg) ok = false; // causal
                float s = sc[cb][r] * scale + (ok ? 0.f : -1e9f);
                sc[cb][r] = s;
                tm[r] = fmaxf(tm[r], s);
            }
        }
#pragma unroll
        for (int off = 1; off < 16; off <<= 1)
#pragma unroll
            for (int r = 0; r < 4; ++r)
                tm[r] = fmaxf(tm[r], __shfl_xor(tm[r], off));

        // online-softmax update
        float alpha_[4], ts[4] = {0.f, 0.f, 0.f, 0.f};
#pragma unroll
        for (int r = 0; r < 4; ++r) {
            const float mn = fmaxf(m_run[r], tm[r]);
            alpha_[r] = __expf(m_run[r] - mn);
            m_run[r] = mn;
            l_run[r] *= alpha_[r];
        }
#pragma unroll
        for (int db = 0; db < 6; ++db)
#pragma unroll
            for (int r = 0; r < 4; ++r)
                oc[db][r] *= alpha_[r];

        // P = exp(S - m), write to LDS (C-layout -> A-layout roundtrip)
#pragma unroll
        for (int cb = 0; cb < 4; ++cb)
#pragma unroll
            for (int r = 0; r < 4; ++r) {
                const float p = __expf(sc[cb][r] - m_run[r]);
                ts[r] += p;
                Ps[(w * 16 + quad * 4 + r) * 72 + cb * 16 + lr] = (bf16)p;
            }
#pragma unroll
        for (int off = 1; off < 16; off <<= 1)
#pragma unroll
            for (int r = 0; r < 4; ++r)
                ts[r] += __shfl_xor(ts[r], off);
#pragma unroll
        for (int r = 0; r < 4; ++r) l_run[r] += ts[r];

        __syncthreads();    // Ps/Vs visible to all lanes

        // O += P @ V
#pragma unroll
        for (int l0 = 0; l0 < 64; l0 += 32) {
            bf16x8 ap = *(const bf16x8*)&Ps[(w * 16 + lr) * 72 + l0 + quad * 8];
#pragma unroll
            for (int db = 0; db < 6; ++db) {
                bf16x8 bv = *(const bf16x8*)&Vs[(db * 16 + lr) * 72 + l0 + quad * 8];
                oc[db] = __builtin_amdgcn_mfma_f32_16x16x32_bf16(ap, bv, oc[db], 0, 0, 0);
            }
        }
    }

    // epilogue: ctx[b][row][h*96 + d] = O / l
#pragma unroll
    for (int r = 0; r < 4; ++r) {
        const float inv = 1.f / l_run[r];
        bf16* orow = ctx + ((size_t)b * 512 + ig[r]) * 768 + h * 96;
#pragma unroll
        for (int db = 0; db < 6; ++db)
            orow[db * 16 + lr] = (bf16)(oc[db][r] * inv);
    }
}

// ---------------------------------------------------------------------------
// transpose fp32 weight [R][C] -> bf16 [C][R]
// ---------------------------------------------------------------------------
__global__ void transpose_w(const float* __restrict__ in, bf16* __restrict__ out,
                            int R, int C)
{
    __shared__ bf16 tile[32][33];
    const int c0 = blockIdx.x * 32, r0 = blockIdx.y * 32;
    const int tx = threadIdx.x & 31, ty = threadIdx.x >> 5;
    for (int i = ty; i < 32; i += 8)
        tile[i][tx] = (bf16)in[(size_t)(r0 + i) * C + c0 + tx];
    __syncthreads();
    for (int i = ty; i < 32; i += 8)
        out[(size_t)(c0 + i) * R + r0 + tx] = tile[tx][i];
}

// fp32 -> bf16 elementwise
__global__ void cvt_bf16(const float* __restrict__ in, bf16* __restrict__ out, int n)
{
    const int idx = blockIdx.x * 256 + threadIdx.x;
    if (idx < n) out[idx] = (bf16)in[idx];
}

// ---------------------------------------------------------------------------
// reductions / LN
// ---------------------------------------------------------------------------
__device__ __forceinline__ void block_reduce_2(float& a, float& b)
{
#pragma unroll
    for (int off = 32; off; off >>= 1) {
        a += __shfl_xor(a, off);
        b += __shfl_xor(b, off);
    }
    __shared__ float sa[4], sb[4];
    const int w = threadIdx.x >> 6;
    if ((threadIdx.x & 63) == 0) { sa[w] = a; sb[w] = b; }
    __syncthreads();
    a = sa[0] + sa[1] + sa[2] + sa[3];
    b = sb[0] + sb[1] + sb[2] + sb[3];
}

// x[row] = LN(concat_src(row) + pos[l] + tok); fp32 inputs, bf16 out
__global__ void embed_ln(const float* __restrict__ qtok, const bf16* __restrict__ gfeat,
                         const float* __restrict__ text, const float* __restrict__ pos,
                         const float* __restrict__ tok, const float* __restrict__ g,
                         const float* __restrict__ bb, bf16* __restrict__ x)
{
    const int row = blockIdx.x;           // b*512 + l
    const int l = row & 511, b = row >> 9;
    const int t = threadIdx.x;

    float vals[3], s = 0.f, sq = 0.f;
#pragma unroll
    for (int c = 0; c < 3; ++c) {
        const int d = t + c * 256;
        float base;
        if (l < NQ)           base = qtok[(size_t)l * DD + d];
        else if (l < TSPLIT)  base = (float)gfeat[((size_t)b * NN_ + (l - NQ)) * DD + d];
        else                  base = text[((size_t)b * TT + (l - TSPLIT)) * DD + d];
        float v = base + pos[(size_t)l * DD + d] + tok[d];
        vals[c] = v; s += v; sq += v * v;
    }
    block_reduce_2(s, sq);
    const float mean = s * (1.f / 768.f);
    const float var = sq * (1.f / 768.f) - mean * mean;
    const float rs = rsqrtf(var + 1e-12f);
    bf16* o = x + (size_t)row * DD;
#pragma unroll
    for (int c = 0; c < 3; ++c) {
        const int d = t + c * 256;
        o[d] = (bf16)((vals[c] - mean) * rs * g[d] + bb[d]);
    }
}

// out[row] = LN(X[row] + Y[row]); safe for out==X; fp32 gains
__global__ void ln_rows(const bf16* __restrict__ X, const bf16* __restrict__ Y,
                        bf16* __restrict__ Out, const float* __restrict__ g,
                        const float* __restrict__ bb)
{
    const int row = blockIdx.x;
    const int t = threadIdx.x;
    const bf16* xr = X + (size_t)row * DD;
    const bf16* yr = Y + (size_t)row * DD;
    float vals[3], s = 0.f, sq = 0.f;
#pragma unroll
    for (int c = 0; c < 3; ++c) {
        const int d = t + c * 256;
        float v = (float)xr[d] + (float)yr[d];
        vals[c] = v; s += v; sq += v * v;
    }
    block_reduce_2(s, sq);
    const float mean = s * (1.f / 768.f);
    const float var = sq * (1.f / 768.f) - mean * mean;
    const float rs = rsqrtf(var + 1e-12f);
    bf16* o = Out + (size_t)row * DD;
#pragma unroll
    for (int c = 0; c < 3; ++c) {
        const int d = t + c * 256;
        o[d] = (bf16)((vals[c] - mean) * rs * g[d] + bb[d]);
    }
}

// d_out[b][t][d] = x[b][TSPLIT+t][d]  (fp32 out)
__global__ void copy_out(const bf16* __restrict__ x, float* __restrict__ out)
{
    const size_t idx = (size_t)blockIdx.x * 256 + threadIdx.x;   // < 16*352*768
    const int d = idx % DD;
    const size_t row = idx / DD;
    const int t = row % TT;
    const int b = row / TT;
    out[idx] = (float)x[((size_t)b * LSEQ + TSPLIT + t) * DD + d];
}

// ---------------------------------------------------------------------------
// host side
// ---------------------------------------------------------------------------
static void launch_gemm(const bf16* A, const bf16* Bt, bf16* C, const float* bias,
                        int M, int K, int lda, int ldb, int ldc,
                        float alpha, int Nstore, int act, hipStream_t stream)
{
    dim3 grid((Nstore + 127) / 128, M / 128, 1);
    if (act)
        gemm_bt<1><<<grid, 256, 0, stream>>>(A, Bt, C, bias, K, lda, ldb, ldc, alpha, Nstore);
    else
        gemm_bt<0><<<grid, 256, 0, stream>>>(A, Bt, C, bias, K, lda, ldb, ldc, alpha, Nstore);
}

extern "C" void kernel_launch(void* const* d_in, const int* in_sizes, int n_in,
                              void* d_out, int out_size, void* d_ws, size_t ws_size,
                              hipStream_t stream)
{
    // Reference dtypes: all float32 except text_atts / graph_mask (int32).
    const float* gnf     = (const float*)d_in[0];
    const float* text    = (const float*)d_in[1];
    const int*   tatts   = (const int*)d_in[2];
    const int*   gmask   = (const int*)d_in[3];
    const float* qtok    = (const float*)d_in[4];
    const float* gproj_w = (const float*)d_in[5];
    const float* gproj_b = (const float*)d_in[6];
    const float* pos     = (const float*)d_in[7];
    const float* tok     = (const float*)d_in[8];
    const float* eg      = (const float*)d_in[9];
    const float* eb      = (const float*)d_in[10];
    const float* qkv_w   = (const float*)d_in[11];
    const float* qkv_b   = (const float*)d_in[12];
    const float* ao_w    = (const float*)d_in[13];
    const float* ao_b    = (const float*)d_in[14];
    const float* ln1g    = (const float*)d_in[15];
    const float* ln1b    = (const float*)d_in[16];
    const float* ff1_w   = (const float*)d_in[17];
    const float* ff1_b   = (const float*)d_in[18];
    const float* ff2_w   = (const float*)d_in[19];
    const float* ff2_b   = (const float*)d_in[20];
    const float* ln2g    = (const float*)d_in[21];
    const float* ln2b    = (const float*)d_in[22];
    float* out = (float*)d_out;

    // ws layout (bf16 elems), 48,758,784 elems = 97.5 MB (ws >= 169 MB verified
    // in round 4 — big path ran). u-region: qkvb (attn) / hbuf (ffn), disjoint.
    bf16* ws   = (bf16*)d_ws;
    bf16* wt1  = ws;                    // 2,359,296
    bf16* wt2  = wt1 + 2359296;         // 2,359,296
    bf16* x    = wt2 + 2359296;         // 6,291,456
    bf16* ctx  = x   + 6291456;         // 6,291,456
    bf16* t1   = ctx + 6291456;         // 6,291,456
    bf16* u    = t1  + 6291456;         // 25,165,824
    bf16* qkvb = u;                     //   18,874,368 (attn phase)
    bf16* hbuf = u;                     //   25,165,824 (ffn phase)
    bf16* gfeat = t1;                   //    1,572,864 (pre-loop)
    bf16* gnfb  = u;                    //    1,572,864 (pre-loop)

    dim3 blk(256);

    // graph projection: gfeat[2048,768] = bf16(gnf) @ bf16(gproj_w) + b
    cvt_bf16<<<6144, blk, 0, stream>>>(gnf, gnfb, 1572864);
    transpose_w<<<dim3(24, 24), blk, 0, stream>>>(gproj_w, wt1, 768, 768);
    launch_gemm(gnfb, wt1, gfeat, gproj_b, 2048, 768, 768, 768, 768,
                1.f, 768, 0, stream);
    embed_ln<<<8192, blk, 0, stream>>>(qtok, gfeat, text, pos, tok, eg, eb, x);

    for (int i = 0; i < NLAYER; ++i) {
        // qkv = x @ qkv_w[i] + b   [8192, 2304]
        transpose_w<<<dim3(72, 24), blk, 0, stream>>>(
            qkv_w + (size_t)i * 768 * 2304, wt1, 768, 2304);
        launch_gemm(x, wt1, qkvb, qkv_b + i * 2304,
                    8192, 768, 768, 768, 2304, 1.f, 2304, 0, stream);
        // fused attention -> ctx [8192, 768]
        flash_attn<<<dim3(8, 128), blk, 0, stream>>>(qkvb, ctx, tatts, gmask);
        // t1 = ctx @ ao_w[i] + b
        transpose_w<<<dim3(24, 24), blk, 0, stream>>>(
            ao_w + (size_t)i * 589824, wt1, 768, 768);
        launch_gemm(ctx, wt1, t1, ao_b + i * 768,
                    8192, 768, 768, 768, 768, 1.f, 768, 0, stream);
        ln_rows<<<8192, blk, 0, stream>>>(x, t1, x, ln1g + i * 768, ln1b + i * 768);

        // ffn
        transpose_w<<<dim3(96, 24), blk, 0, stream>>>(
            ff1_w + (size_t)i * 2359296, wt1, 768, 3072);
        transpose_w<<<dim3(24, 96), blk, 0, stream>>>(
            ff2_w + (size_t)i * 2359296, wt2, 3072, 768);
        launch_gemm(x, wt1, hbuf, ff1_b + i * 3072,
                    8192, 768, 768, 768, 3072, 1.f, 3072, 1, stream);
        launch_gemm(hbuf, wt2, t1, ff2_b + i * 768,
                    8192, 3072, 3072, 3072, 768, 1.f, 768, 0, stream);
        ln_rows<<<8192, blk, 0, stream>>>(x, t1, x, ln2g + i * 768, ln2b + i * 768);
    }

    copy_out<<<16896, blk, 0, stream>>>(x, out);

    (void)in_sizes; (void)n_in; (void)out_size; (void)ws_size;
}

// Round 4
// 2140.777 us; speedup vs baseline: 1.0802x; 1.0184x over previous
//
#include <hip/hip_runtime.h>
#include <math.h>

typedef __bf16 bf16;
typedef __bf16 bf16x8 __attribute__((ext_vector_type(8)));
typedef float f32x4 __attribute__((ext_vector_type(4)));

// Problem dims
#define NQ   32
#define NN_  128
#define TT   352
#define DD   768
#define NH   8
#define HDIM 96
#define LSEQ 512
#define TSPLIT 160          // NQ + NN
#define FFD  3072
#define NLAYER 6
#define NBATCH 16

// ---------------------------------------------------------------------------
// R4 theory: R2 vs R3 A/B proved pipeline depth is NOT the limiter (81 us
// either way); occupancy pinned ~9 waves/CU in both -> latency-bound from
// thin TLP + grid-shape tail waste. Fixes:
//  * gemm_bt8: 8-wave 256Mx128N tile for qkv/FF1 (2 blk/CU = 16 waves/CU),
//    same verified staging/fragment idioms, counted vmcnt(3), setprio (T5).
//  * gemm_bt: unchanged R3 structure + gridDim.z split-K for ao/FF2
//    (384-block grids = 1.5 gens -> 768 = 3.0 gens, no tail), partials
//    summed in ln_rows3.
// SQ_LDS_BANK_CONFLICT 4,718,592 = inherent global_load_lds write
// serialization (16 wave-writes x 8 wraps / kstep) — not a read conflict.
// ---------------------------------------------------------------------------
#define GLOAD(srcp, dstp)                                                     \
    __builtin_amdgcn_global_load_lds(                                         \
        (const __attribute__((address_space(1))) void*)(srcp),                \
        (__attribute__((address_space(3))) void*)(dstp), 16, 0, 0)

// ---------------------------------------------------------------------------
// 128x128 tile, 4 waves, BK=32, 3-buffer counted-vmcnt pipeline.
// Optional K-split over gridDim.z: K arg = per-split K; A/Bt column offset
// z*K; C offset z*zstride; bias applied only at z==0 (ACT must be 0 if z>1).
// ---------------------------------------------------------------------------
template <int ACT>
__global__ __launch_bounds__(256) void gemm_bt(
    const bf16* __restrict__ A, const bf16* __restrict__ Bt,
    bf16* __restrict__ C, const float* __restrict__ bias,
    int K, int lda, int ldb, int ldc, float alpha, int Nstore, size_t zstride)
{
    __shared__ __attribute__((aligned(16))) bf16 As[3 * 4096];
    __shared__ __attribute__((aligned(16))) bf16 Bs[3 * 4096];

    const int z = blockIdx.z;
    A  += (size_t)z * K;          // column offset into A[M][lda]
    Bt += (size_t)z * K;          // column offset into Bt[N][ldb]
    C  += (size_t)z * zstride;

    const int n0 = blockIdx.x * 128, m0 = blockIdx.y * 128;
    const int t = threadIdx.x;
    const int w = t >> 6, l = t & 63;
    const int wm = w >> 1, wn = w & 1;
    const int lr = l & 15, quad = l >> 4;

    f32x4 acc[4][4] = {};

    const int f0 = w * 1024 + l * 8;
    const int ra0 = f0 >> 5, ca0 = f0 & 31;
    const int ra1 = (f0 + 512) >> 5, ca1 = (f0 + 512) & 31;
    const bf16* a0 = A  + (size_t)(m0 + ra0) * lda + ca0;
    const bf16* a1 = A  + (size_t)(m0 + ra1) * lda + ca1;
    const bf16* b0 = Bt + (size_t)(n0 + ra0) * ldb + ca0;
    const bf16* b1 = Bt + (size_t)(n0 + ra1) * ldb + ca1;

    const int nt = K >> 5;              // >= 3 for all call sites

    // prologue: stage tiles 0,1 into buffers 0,1
    {
        bf16* pA = &As[w * 1024];
        bf16* pB = &Bs[w * 1024];
        GLOAD(a0, pA);        GLOAD(a1, pA + 512);
        GLOAD(b0, pB);        GLOAD(b1, pB + 512);
        pA += 4096;  pB += 4096;
        GLOAD(a0 + 32, pA);   GLOAD(a1 + 32, pA + 512);
        GLOAD(b0 + 32, pB);   GLOAD(b1 + 32, pB + 512);
    }

    int cb = 0, wb = 2;
    for (int T = 0; T < nt; ++T) {
        if (T == nt - 1) {
            asm volatile("s_waitcnt vmcnt(0)" ::: "memory");
        } else {
            asm volatile("s_waitcnt vmcnt(4)" ::: "memory");
        }
        __builtin_amdgcn_s_barrier();
        __builtin_amdgcn_sched_barrier(0);

        if (T + 2 < nt) {
            const int k0 = (T + 2) << 5;
            bf16* pA = &As[wb * 4096 + w * 1024];
            bf16* pB = &Bs[wb * 4096 + w * 1024];
            GLOAD(a0 + k0, pA);   GLOAD(a1 + k0, pA + 512);
            GLOAD(b0 + k0, pB);   GLOAD(b1 + k0, pB + 512);
        }

        const int cur = cb << 12;
        bf16x8 af[4], bf_[4];
#pragma unroll
        for (int i = 0; i < 4; ++i)
            af[i] = *(const bf16x8*)&As[cur + (wm * 64 + i * 16 + lr) * 32 + quad * 8];
#pragma unroll
        for (int j = 0; j < 4; ++j)
            bf_[j] = *(const bf16x8*)&Bs[cur + (wn * 64 + j * 16 + lr) * 32 + quad * 8];
#pragma unroll
        for (int i = 0; i < 4; ++i)
#pragma unroll
            for (int j = 0; j < 4; ++j)
                acc[i][j] = __builtin_amdgcn_mfma_f32_16x16x32_bf16(af[i], bf_[j], acc[i][j], 0, 0, 0);

        cb = (cb == 2) ? 0 : cb + 1;
        wb = (wb == 2) ? 0 : wb + 1;
    }

    const bool dob = (z == 0);
#pragma unroll
    for (int i = 0; i < 4; ++i) {
        const int grow = m0 + wm * 64 + i * 16 + quad * 4;
#pragma unroll
        for (int j = 0; j < 4; ++j) {
            const int gcol = n0 + wn * 64 + j * 16 + lr;
            if (gcol >= Nstore) continue;
            float bv = (bias && dob) ? bias[gcol] : 0.0f;
#pragma unroll
            for (int r = 0; r < 4; ++r) {
                float v = acc[i][j][r] * alpha + bv;
                if (ACT == 1) v = 0.5f * v * (1.0f + erff(v * 0.70710678118654752f));
                C[(size_t)(grow + r) * ldc + gcol] = (bf16)v;
            }
        }
    }
}

// ---------------------------------------------------------------------------
// 256Mx128N tile, 8 waves (4x2 of 64x64), BK=32, 3-buffer counted-vmcnt.
// LDS 72 KB -> 2 blocks/CU = 16 waves/CU. 3 GLOADs/tile/wave -> vmcnt(3).
// ---------------------------------------------------------------------------
template <int ACT>
__global__ __launch_bounds__(512) void gemm_bt8(
    const bf16* __restrict__ A, const bf16* __restrict__ Bt,
    bf16* __restrict__ C, const float* __restrict__ bias,
    int K, int lda, int ldb, int ldc, float alpha, int Nstore)
{
    __shared__ __attribute__((aligned(16))) bf16 As[3 * 8192];   // 3 x 256x32
    __shared__ __attribute__((aligned(16))) bf16 Bs[3 * 4096];   // 3 x 128x32

    const int n0 = blockIdx.x * 128, m0 = blockIdx.y * 256;
    const int t = threadIdx.x;
    const int w = t >> 6, l = t & 63;          // w 0..7
    const int wm = w >> 1, wn = w & 1;         // wm 0..3, wn 0..1
    const int lr = l & 15, quad = l >> 4;

    f32x4 acc[4][4] = {};

    // A staged in 2 rounds of 8KB (512 thr x 16B); B in 1 round.
    const int f0 = w * 512 + l * 8;
    const int ra0 = f0 >> 5,          ca0 = f0 & 31;            // rows 0..127
    const int ra1 = ((f0 + 4096) >> 5), ca1 = f0 & 31;          // rows 128..255
    const bf16* a0 = A  + (size_t)(m0 + ra0) * lda + ca0;
    const bf16* a1 = A  + (size_t)(m0 + ra1) * lda + ca1;
    const bf16* b0 = Bt + (size_t)(n0 + ra0) * ldb + ca0;

    const int nt = K >> 5;

    // prologue: tiles 0,1
    {
        bf16* pA = &As[w * 512];
        bf16* pB = &Bs[w * 512];
        GLOAD(a0, pA);        GLOAD(a1, pA + 4096);   GLOAD(b0, pB);
        pA += 8192;  pB += 4096;
        GLOAD(a0 + 32, pA);   GLOAD(a1 + 32, pA + 4096);  GLOAD(b0 + 32, pB);
    }

    int cb = 0, wb = 2;
    for (int T = 0; T < nt; ++T) {
        if (T == nt - 1) {
            asm volatile("s_waitcnt vmcnt(0)" ::: "memory");
        } else {
            asm volatile("s_waitcnt vmcnt(3)" ::: "memory");
        }
        __builtin_amdgcn_s_barrier();
        __builtin_amdgcn_sched_barrier(0);

        if (T + 2 < nt) {
            const int k0 = (T + 2) << 5;
            bf16* pA = &As[wb * 8192 + w * 512];
            bf16* pB = &Bs[wb * 4096 + w * 512];
            GLOAD(a0 + k0, pA);  GLOAD(a1 + k0, pA + 4096);  GLOAD(b0 + k0, pB);
        }

        const int curA = cb * 8192, curB = cb * 4096;
        bf16x8 af[4], bf_[4];
#pragma unroll
        for (int i = 0; i < 4; ++i)
            af[i] = *(const bf16x8*)&As[curA + (wm * 64 + i * 16 + lr) * 32 + quad * 8];
#pragma unroll
        for (int j = 0; j < 4; ++j)
            bf_[j] = *(const bf16x8*)&Bs[curB + (wn * 64 + j * 16 + lr) * 32 + quad * 8];

        __builtin_amdgcn_s_setprio(1);
#pragma unroll
        for (int i = 0; i < 4; ++i)
#pragma unroll
            for (int j = 0; j < 4; ++j)
                acc[i][j] = __builtin_amdgcn_mfma_f32_16x16x32_bf16(af[i], bf_[j], acc[i][j], 0, 0, 0);
        __builtin_amdgcn_s_setprio(0);

        cb = (cb == 2) ? 0 : cb + 1;
        wb = (wb == 2) ? 0 : wb + 1;
    }

#pragma unroll
    for (int i = 0; i < 4; ++i) {
        const int grow = m0 + wm * 64 + i * 16 + quad * 4;
#pragma unroll
        for (int j = 0; j < 4; ++j) {
            const int gcol = n0 + wn * 64 + j * 16 + lr;
            if (gcol >= Nstore) continue;
            float bv = bias ? bias[gcol] : 0.0f;
#pragma unroll
            for (int r = 0; r < 4; ++r) {
                float v = acc[i][j][r] * alpha + bv;
                if (ACT == 1) v = 0.5f * v * (1.0f + erff(v * 0.70710678118654752f));
                C[(size_t)(grow + r) * ldc + gcol] = (bf16)v;
            }
        }
    }
}

// ---------------------------------------------------------------------------
// Flash attention with ITG prefix-LM mask (unchanged from R3).
// ---------------------------------------------------------------------------
__global__ __launch_bounds__(256) void flash_attn(
    const bf16* __restrict__ qkv, bf16* __restrict__ ctx,
    const int* __restrict__ tatts, const int* __restrict__ gmask)
{
    __shared__ __attribute__((aligned(16))) bf16 Qs[64 * 104];
    __shared__ __attribute__((aligned(16))) bf16 Ks[64 * 104];
    __shared__ __attribute__((aligned(16))) bf16 Vs[96 * 72];   // V^T tile
    __shared__ __attribute__((aligned(16))) bf16 Ps[64 * 72];
    __shared__ int keep[512];

    const int qt = blockIdx.x;       // 0..7
    const int bh = blockIdx.y;       // 0..127
    const int b = bh >> 3, h = bh & 7;
    const int q0 = qt * 64;
    const int t = threadIdx.x;
    const int w = t >> 6, l = t & 63;
    const int lr = l & 15, quad = l >> 4;
    const float scale = 0.10206207261596577f;  // 1/sqrt(96)

    const bf16* qbase = qkv + (size_t)b * 512 * 2304 + h * 96;
    const bf16* kbase = qbase + 768;
    const bf16* vbase = qbase + 1536;

    for (int j = t; j < 512; j += 256)
        keep[j] = (j < NQ) ? 1 : (j < TSPLIT ? gmask[b * NN_ + j - NQ]
                                             : tatts[b * TT + j - TSPLIT]);

#pragma unroll
    for (int c = 0; c < 3; ++c) {
        const int idx = t * 8 + c * 2048;
        const int r = idx / 96, d = idx % 96;
        *(bf16x8*)&Qs[r * 104 + d] =
            *(const bf16x8*)&qbase[(size_t)(q0 + r) * 2304 + d];
    }
    __syncthreads();

    int ki[4];
    int ig[4];
#pragma unroll
    for (int r = 0; r < 4; ++r) {
        ig[r] = q0 + w * 16 + quad * 4 + r;
        ki[r] = keep[ig[r]];
    }

    float m_run[4] = {-1e30f, -1e30f, -1e30f, -1e30f};
    float l_run[4] = {0.f, 0.f, 0.f, 0.f};
    f32x4 oc[6] = {};

    const int JMAX = (qt < 3) ? 128 : q0;
    for (int j0 = 0; j0 <= JMAX; j0 += 64) {
        __syncthreads();
#pragma unroll
        for (int c = 0; c < 3; ++c) {
            const int idx = t * 8 + c * 2048;
            const int r = idx / 96, d = idx % 96;
            *(bf16x8*)&Ks[r * 104 + d] =
                *(const bf16x8*)&kbase[(size_t)(j0 + r) * 2304 + d];
            bf16x8 vv = *(const bf16x8*)&vbase[(size_t)(j0 + r) * 2304 + d];
#pragma unroll
            for (int jj = 0; jj < 8; ++jj)
                Vs[(d + jj) * 72 + r] = vv[jj];
        }
        __syncthreads();

        bf16x8 aq[3];
#pragma unroll
        for (int ds = 0; ds < 3; ++ds)
            aq[ds] = *(const bf16x8*)&Qs[(w * 16 + lr) * 104 + ds * 32 + quad * 8];
        f32x4 sc[4];
#pragma unroll
        for (int cb = 0; cb < 4; ++cb) {
            f32x4 a = {};
#pragma unroll
            for (int ds = 0; ds < 3; ++ds) {
                bf16x8 bk = *(const bf16x8*)&Ks[(cb * 16 + lr) * 104 + ds * 32 + quad * 8];
                a = __builtin_amdgcn_mfma_f32_16x16x32_bf16(aq[ds], bk, a, 0, 0, 0);
            }
            sc[cb] = a;
        }

        float tm[4] = {-1e30f, -1e30f, -1e30f, -1e30f};
#pragma unroll
        for (int cb = 0; cb < 4; ++cb) {
            const int jg = j0 + cb * 16 + lr;
            const int kj = keep[jg];
#pragma unroll
            for (int r = 0; r < 4; ++r) {
                const int i = ig[r];
                bool ok = ki[r] && kj;
                if (i < TSPLIT && jg >= TSPLIT) ok = false;
                if (i >= TSPLIT && jg >= TSPLIT && i < jg) ok = false;
                float s = sc[cb][r] * scale + (ok ? 0.f : -1e9f);
                sc[cb][r] = s;
                tm[r] = fmaxf(tm[r], s);
            }
        }
#pragma unroll
        for (int off = 1; off < 16; off <<= 1)
#pragma unroll
            for (int r = 0; r < 4; ++r)
                tm[r] = fmaxf(tm[r], __shfl_xor(tm[r], off));

        float alpha_[4], ts[4] = {0.f, 0.f, 0.f, 0.f};
#pragma unroll
        for (int r = 0; r < 4; ++r) {
            const float mn = fmaxf(m_run[r], tm[r]);
            alpha_[r] = __expf(m_run[r] - mn);
            m_run[r] = mn;
            l_run[r] *= alpha_[r];
        }
#pragma unroll
        for (int db = 0; db < 6; ++db)
#pragma unroll
            for (int r = 0; r < 4; ++r)
                oc[db][r] *= alpha_[r];

#pragma unroll
        for (int cb = 0; cb < 4; ++cb)
#pragma unroll
            for (int r = 0; r < 4; ++r) {
                const float p = __expf(sc[cb][r] - m_run[r]);
                ts[r] += p;
                Ps[(w * 16 + quad * 4 + r) * 72 + cb * 16 + lr] = (bf16)p;
            }
#pragma unroll
        for (int off = 1; off < 16; off <<= 1)
#pragma unroll
            for (int r = 0; r < 4; ++r)
                ts[r] += __shfl_xor(ts[r], off);
#pragma unroll
        for (int r = 0; r < 4; ++r) l_run[r] += ts[r];

        __syncthreads();

#pragma unroll
        for (int l0 = 0; l0 < 64; l0 += 32) {
            bf16x8 ap = *(const bf16x8*)&Ps[(w * 16 + lr) * 72 + l0 + quad * 8];
#pragma unroll
            for (int db = 0; db < 6; ++db) {
                bf16x8 bv = *(const bf16x8*)&Vs[(db * 16 + lr) * 72 + l0 + quad * 8];
                oc[db] = __builtin_amdgcn_mfma_f32_16x16x32_bf16(ap, bv, oc[db], 0, 0, 0);
            }
        }
    }

#pragma unroll
    for (int r = 0; r < 4; ++r) {
        const float inv = 1.f / l_run[r];
        bf16* orow = ctx + ((size_t)b * 512 + ig[r]) * 768 + h * 96;
#pragma unroll
        for (int db = 0; db < 6; ++db)
            orow[db * 16 + lr] = (bf16)(oc[db][r] * inv);
    }
}

// ---------------------------------------------------------------------------
// transpose fp32 weight [R][C] -> bf16 [C][R]
// ---------------------------------------------------------------------------
__global__ void transpose_w(const float* __restrict__ in, bf16* __restrict__ out,
                            int R, int C)
{
    __shared__ bf16 tile[32][33];
    const int c0 = blockIdx.x * 32, r0 = blockIdx.y * 32;
    const int tx = threadIdx.x & 31, ty = threadIdx.x >> 5;
    for (int i = ty; i < 32; i += 8)
        tile[i][tx] = (bf16)in[(size_t)(r0 + i) * C + c0 + tx];
    __syncthreads();
    for (int i = ty; i < 32; i += 8)
        out[(size_t)(c0 + i) * R + r0 + tx] = tile[tx][i];
}

// fp32 -> bf16 elementwise
__global__ void cvt_bf16(const float* __restrict__ in, bf16* __restrict__ out, int n)
{
    const int idx = blockIdx.x * 256 + threadIdx.x;
    if (idx < n) out[idx] = (bf16)in[idx];
}

// ---------------------------------------------------------------------------
// reductions / LN
// ---------------------------------------------------------------------------
__device__ __forceinline__ void block_reduce_2(float& a, float& b)
{
#pragma unroll
    for (int off = 32; off; off >>= 1) {
        a += __shfl_xor(a, off);
        b += __shfl_xor(b, off);
    }
    __shared__ float sa[4], sb[4];
    const int w = threadIdx.x >> 6;
    if ((threadIdx.x & 63) == 0) { sa[w] = a; sb[w] = b; }
    __syncthreads();
    a = sa[0] + sa[1] + sa[2] + sa[3];
    b = sb[0] + sb[1] + sb[2] + sb[3];
}

// x[row] = LN(concat_src(row) + pos[l] + tok); fp32 inputs, bf16 out
__global__ void embed_ln(const float* __restrict__ qtok, const bf16* __restrict__ gfeat,
                         const float* __restrict__ text, const float* __restrict__ pos,
                         const float* __restrict__ tok, const float* __restrict__ g,
                         const float* __restrict__ bb, bf16* __restrict__ x)
{
    const int row = blockIdx.x;           // b*512 + l
    const int l = row & 511, b = row >> 9;
    const int t = threadIdx.x;

    float vals[3], s = 0.f, sq = 0.f;
#pragma unroll
    for (int c = 0; c < 3; ++c) {
        const int d = t + c * 256;
        float base;
        if (l < NQ)           base = qtok[(size_t)l * DD + d];
        else if (l < TSPLIT)  base = (float)gfeat[((size_t)b * NN_ + (l - NQ)) * DD + d];
        else                  base = text[((size_t)b * TT + (l - TSPLIT)) * DD + d];
        float v = base + pos[(size_t)l * DD + d] + tok[d];
        vals[c] = v; s += v; sq += v * v;
    }
    block_reduce_2(s, sq);
    const float mean = s * (1.f / 768.f);
    const float var = sq * (1.f / 768.f) - mean * mean;
    const float rs = rsqrtf(var + 1e-12f);
    bf16* o = x + (size_t)row * DD;
#pragma unroll
    for (int c = 0; c < 3; ++c) {
        const int d = t + c * 256;
        o[d] = (bf16)((vals[c] - mean) * rs * g[d] + bb[d]);
    }
}

// out[row] = LN(X[row] + Y[row] + Z[row]); safe for out==X; fp32 gains
__global__ void ln_rows3(const bf16* __restrict__ X, const bf16* __restrict__ Y,
                         const bf16* __restrict__ Z, bf16* __restrict__ Out,
                         const float* __restrict__ g, const float* __restrict__ bb)
{
    const int row = blockIdx.x;
    const int t = threadIdx.x;
    const bf16* xr = X + (size_t)row * DD;
    const bf16* yr = Y + (size_t)row * DD;
    const bf16* zr = Z + (size_t)row * DD;
    float vals[3], s = 0.f, sq = 0.f;
#pragma unroll
    for (int c = 0; c < 3; ++c) {
        const int d = t + c * 256;
        float v = (float)xr[d] + (float)yr[d] + (float)zr[d];
        vals[c] = v; s += v; sq += v * v;
    }
    block_reduce_2(s, sq);
    const float mean = s * (1.f / 768.f);
    const float var = sq * (1.f / 768.f) - mean * mean;
    const float rs = rsqrtf(var + 1e-12f);
    bf16* o = Out + (size_t)row * DD;
#pragma unroll
    for (int c = 0; c < 3; ++c) {
        const int d = t + c * 256;
        o[d] = (bf16)((vals[c] - mean) * rs * g[d] + bb[d]);
    }
}

// d_out[b][t][d] = x[b][TSPLIT+t][d]  (fp32 out)
__global__ void copy_out(const bf16* __restrict__ x, float* __restrict__ out)
{
    const size_t idx = (size_t)blockIdx.x * 256 + threadIdx.x;   // < 16*352*768
    const int d = idx % DD;
    const size_t row = idx / DD;
    const int t = row % TT;
    const int b = row / TT;
    out[idx] = (float)x[((size_t)b * LSEQ + TSPLIT + t) * DD + d];
}

// ---------------------------------------------------------------------------
// host side
// ---------------------------------------------------------------------------
static void launch_gemm(const bf16* A, const bf16* Bt, bf16* C, const float* bias,
                        int M, int K, int lda, int ldb, int ldc,
                        float alpha, int Nstore, int act, int ksplit, size_t zstride,
                        hipStream_t stream)
{
    dim3 grid((Nstore + 127) / 128, M / 128, ksplit);
    if (act)
        gemm_bt<1><<<grid, 256, 0, stream>>>(A, Bt, C, bias, K / ksplit, lda, ldb, ldc, alpha, Nstore, zstride);
    else
        gemm_bt<0><<<grid, 256, 0, stream>>>(A, Bt, C, bias, K / ksplit, lda, ldb, ldc, alpha, Nstore, zstride);
}

static void launch_gemm8(const bf16* A, const bf16* Bt, bf16* C, const float* bias,
                         int M, int K, int lda, int ldb, int ldc,
                         float alpha, int Nstore, int act, hipStream_t stream)
{
    dim3 grid((Nstore + 127) / 128, M / 256, 1);
    if (act)
        gemm_bt8<1><<<grid, 512, 0, stream>>>(A, Bt, C, bias, K, lda, ldb, ldc, alpha, Nstore);
    else
        gemm_bt8<0><<<grid, 512, 0, stream>>>(A, Bt, C, bias, K, lda, ldb, ldc, alpha, Nstore);
}

extern "C" void kernel_launch(void* const* d_in, const int* in_sizes, int n_in,
                              void* d_out, int out_size, void* d_ws, size_t ws_size,
                              hipStream_t stream)
{
    // Reference dtypes: all float32 except text_atts / graph_mask (int32).
    const float* gnf     = (const float*)d_in[0];
    const float* text    = (const float*)d_in[1];
    const int*   tatts   = (const int*)d_in[2];
    const int*   gmask   = (const int*)d_in[3];
    const float* qtok    = (const float*)d_in[4];
    const float* gproj_w = (const float*)d_in[5];
    const float* gproj_b = (const float*)d_in[6];
    const float* pos     = (const float*)d_in[7];
    const float* tok     = (const float*)d_in[8];
    const float* eg      = (const float*)d_in[9];
    const float* eb      = (const float*)d_in[10];
    const float* qkv_w   = (const float*)d_in[11];
    const float* qkv_b   = (const float*)d_in[12];
    const float* ao_w    = (const float*)d_in[13];
    const float* ao_b    = (const float*)d_in[14];
    const float* ln1g    = (const float*)d_in[15];
    const float* ln1b    = (const float*)d_in[16];
    const float* ff1_w   = (const float*)d_in[17];
    const float* ff1_b   = (const float*)d_in[18];
    const float* ff2_w   = (const float*)d_in[19];
    const float* ff2_b   = (const float*)d_in[20];
    const float* ln2g    = (const float*)d_in[21];
    const float* ln2b    = (const float*)d_in[22];
    float* out = (float*)d_out;

    // ws layout (bf16 elems): 55,050,240 elems = 110.1 MB (ws >= 169 MB).
    // u-region: qkvb (attn) / hbuf (ffn), disjoint in time. t2 sits past
    // hbuf's 25.17M so split-K z=1 writes never alias the GEMM's A operand.
    bf16* ws   = (bf16*)d_ws;
    bf16* wt1  = ws;                    // 2,359,296
    bf16* wt2  = wt1 + 2359296;         // 2,359,296
    bf16* x    = wt2 + 2359296;         // 6,291,456
    bf16* ctx  = x   + 6291456;         // 6,291,456
    bf16* t1   = ctx + 6291456;         // 6,291,456
    bf16* u    = t1  + 6291456;         // 25,165,824
    bf16* qkvb = u;                     //   18,874,368 (attn phase)
    bf16* hbuf = u;                     //   25,165,824 (ffn phase)
    bf16* t2   = u   + 25165824;        // 6,291,456 (split-K partial z=1)
    bf16* gfeat = t1;                   //    1,572,864 (pre-loop)
    bf16* gnfb  = u;                    //    1,572,864 (pre-loop)
    const size_t ZST = (size_t)(t2 - t1);   // 31,457,280 elems

    dim3 blk(256);

    // graph projection: gfeat[2048,768] = bf16(gnf) @ bf16(gproj_w) + b
    cvt_bf16<<<6144, blk, 0, stream>>>(gnf, gnfb, 1572864);
    transpose_w<<<dim3(24, 24), blk, 0, stream>>>(gproj_w, wt1, 768, 768);
    launch_gemm(gnfb, wt1, gfeat, gproj_b, 2048, 768, 768, 768, 768,
                1.f, 768, 0, 1, 0, stream);
    embed_ln<<<8192, blk, 0, stream>>>(qtok, gfeat, text, pos, tok, eg, eb, x);

    for (int i = 0; i < NLAYER; ++i) {
        // qkv = x @ qkv_w[i] + b   [8192, 2304]   (8-wave kernel)
        transpose_w<<<dim3(72, 24), blk, 0, stream>>>(
            qkv_w + (size_t)i * 768 * 2304, wt1, 768, 2304);
        launch_gemm8(x, wt1, qkvb, qkv_b + i * 2304,
                     8192, 768, 768, 768, 2304, 1.f, 2304, 0, stream);
        // fused attention -> ctx [8192, 768]
        flash_attn<<<dim3(8, 128), blk, 0, stream>>>(qkvb, ctx, tatts, gmask);
        // t1/t2 = split-K partials of ctx @ ao_w[i] (+ b at z=0)
        transpose_w<<<dim3(24, 24), blk, 0, stream>>>(
            ao_w + (size_t)i * 589824, wt1, 768, 768);
        launch_gemm(ctx, wt1, t1, ao_b + i * 768,
                    8192, 768, 768, 768, 768, 1.f, 768, 0, 2, ZST, stream);
        ln_rows3<<<8192, blk, 0, stream>>>(x, t1, t2, x, ln1g + i * 768, ln1b + i * 768);

        // ffn
        transpose_w<<<dim3(96, 24), blk, 0, stream>>>(
            ff1_w + (size_t)i * 2359296, wt1, 768, 3072);
        transpose_w<<<dim3(24, 96), blk, 0, stream>>>(
            ff2_w + (size_t)i * 2359296, wt2, 3072, 768);
        launch_gemm8(x, wt1, hbuf, ff1_b + i * 3072,
                     8192, 768, 768, 768, 3072, 1.f, 3072, 1, stream);
        launch_gemm(hbuf, wt2, t1, ff2_b + i * 768,
                    8192, 3072, 3072, 3072, 768, 1.f, 768, 0, 2, ZST, stream);
        ln_rows3<<<8192, blk, 0, stream>>>(x, t1, t2, x, ln2g + i * 768, ln2b + i * 768);
    }

    copy_out<<<16896, blk, 0, stream>>>(x, out);

    (void)in_sizes; (void)n_in; (void)out_size; (void)ws_size;
}